// Round 8
// baseline (957.624 us; speedup 1.0000x reference)
//
#include <hip/hip_runtime.h>
#include <math.h>

// Problem constants
#define NN     302      // state dim (N_ROOMS + 2)
#define MM     301      // input dim (N_ROOMS + 1)
#define NROOMS 300
#define NP     320      // padded dim
#define TS     59999    // number of steps
#define KN     2001     // tout knots
#define DTH    30.0f

// Time-chunking (L_CHUNK=128; two chains per WG share one register-resident
// P copy).  r15: refill engine widened to 16 waves / 1024 threads — r14
// post-mortem: VGPR_Count=124 < 200 P-floats/thread proved P was being
// rematerialized from L2 every step (the ~1500cyc/step stall).  20 cols/wave
// -> 100 P-floats/thread fits the 128-VGPR cap of launch_bounds(1024), and
// 16 waves = 4 waves/SIMD doubles latency hiding.
#define L_CHUNK 128     // steps per chunk (level 1)
#define N_CHUNK 469     // ceil(59999/128) chunks
#define N_WG2   235     // refill WGs (2 chains each)
#define N_BND   468     // boundary steps
#define NB_PAD  480     // padded boundary count (30 groups of 16)
#define N_GRP   30      // level-2 groups
#define NSCAN   29      // level-2 boundary-chain steps

// Workspace layout (in floats)
#define WS_M    0        // 102400
#define WS_M2   102400   // 102400
#define WS_P    204800   // 102400
#define WS_UV   307200   // 1600
#define WS_B0C  308800   // 640
#define WS_TAU  309440   // 240000 (float4 x 59999)
#define WS_W    549440   // 5 x 128 x 320 = 204800
#define WS_G    754240   // 480 x 320 = 153600
#define WS_Y    907840   // 469 x 320 = 150080
#define WS_Z    1057920  // 30 x 320 = 9600
#define WS_SA   1067520  // 240 x 320 = 76800
#define WS_SB   1144320  // 120 x 320 = 38400
#define WS_PL   1182720  // 102400  P^128 row-major
#define WS_PA   1285120  // 102400  ladder ping
#define WS_PB   1387520  // 102400  ladder pong
#define WS_PT   1489920  // 12 x 102400 (transposed powers, slot j = (P^(2^j))^T)
#define WS_MT   2718720  // 102400  M^T
                         // total 2821120 floats = 11.28 MB

typedef float vf2 __attribute__((ext_vector_type(2)));

#define ENGINE_LO __launch_bounds__(512) __attribute__((amdgpu_waves_per_eu(2, 2)))
#define ENGINE16  __launch_bounds__(1024)
#define PKFMA(acc, a, b) asm("v_pk_fma_f32 %0, %1, %2, %0" : "+v"(acc) : "v"(a), "v"(b))
#define PIN4(a, b, c, d) asm volatile("" : "+v"(a), "+v"(b), "+v"(c), "+v"(d))
#define PIN2(a, b) asm volatile("" : "+v"(a), "+v"(b))

// ---------------------------------------------------------------------------
// Phase-A mega-kernel: blocks 0..319 buildrow; 320..383 b0c (5 rows/block);
// 384..618 tau.  All independent — one launch, whole-GPU utilization.
__global__ __launch_bounds__(320) void phaseA_kernel(
    const float* __restrict__ params, const float* __restrict__ tlo,
    const float* __restrict__ thi, const float* __restrict__ B,
    const float* __restrict__ tout_t, const float* __restrict__ tout_v,
    const int* __restrict__ t0p,
    float* __restrict__ M, float* __restrict__ MT,
    float* __restrict__ b0c, float4* __restrict__ tau)
{
    __shared__ float red[5];
    __shared__ float Qs[NROOMS];
    const int b = blockIdx.x;
    const int tid = threadIdx.x;

    if (b < 320) {
        const int r = b;
        const int c = tid;
        float wv = 0.0f;
        if (r < NN && c < NN) {
            const int idx = r * NN + c;
            const float x = 1.0f / (1.0f + expf(-params[idx]));
            wv = tlo[idx] + (thi[idx] - tlo[idx]) * x;
        }
        float s = fabsf(wv);
        #pragma unroll
        for (int off = 32; off > 0; off >>= 1) s += __shfl_xor(s, off, 64);
        if ((c & 63) == 0) red[c >> 6] = s;
        __syncthreads();
        const float rs = red[0] + red[1] + red[2] + red[3] + red[4];
        float v = DTH * wv;
        if (r == c) v -= DTH * rs;
        M[r * NP + c] = v;
        MT[(size_t)c * NP + r] = v;
    } else if (b < 384) {
        for (int q = tid; q < NROOMS; q += 320) {
            const int idx = NN * NN + q;
            const float x = 1.0f / (1.0f + expf(-params[idx]));
            Qs[q] = tlo[idx] + (thi[idx] - tlo[idx]) * x;
        }
        __syncthreads();
        const int w = tid >> 6, l = tid & 63;
        const int r = (b - 320) * 5 + w;
        if (r >= NN) {
            if (l == 0) { b0c[r] = 0.0f; b0c[NP + r] = 0.0f; }
            return;
        }
        float s = 0.0f;
        for (int q = l; q < NROOMS; q += 64) s = fmaf(B[r * MM + 1 + q], Qs[q], s);
        #pragma unroll
        for (int off = 32; off > 0; off >>= 1) s += __shfl_xor(s, off, 64);
        if (l == 0) { b0c[r] = B[r * MM]; b0c[NP + r] = s; }
    } else {
        if (tid >= 256) return;
        const int n = (b - 384) * 256 + tid;
        if (n >= TS) return;
        const float tbase = 30.0f * (float)n + (float)(*t0p);
        float r[4];
        #pragma unroll
        for (int st = 0; st < 4; ++st) {
            const float x = tbase + 10.0f * (float)st;
            float res;
            if (x <= tout_t[0])            res = tout_v[0];
            else if (x >= tout_t[KN - 1])  res = tout_v[KN - 1];
            else {
                int k = (int)(x * (1.0f / 900.0f));
                if (k > KN - 2) k = KN - 2;
                if (k < 0) k = 0;
                if (x < tout_t[k] && k > 0) --k;
                else if (x >= tout_t[k + 1] && k < KN - 2) ++k;
                const float tk = tout_t[k], tk1 = tout_t[k + 1];
                const float wgt = (x - tk) / (tk1 - tk);
                res = tout_v[k] + wgt * (tout_v[k + 1] - tout_v[k]);
            }
            r[st] = res;
        }
        tau[n] = make_float4(r[0], r[1], r[2], r[3]);
    }
}

// ---------------------------------------------------------------------------
// M2 = M@M (blocks 0..79) fused with vec_kernel (block 80).
__global__ __launch_bounds__(320) void mm4r_vec_kernel(
    const float* __restrict__ A, float* __restrict__ C,
    const float* __restrict__ MT, const float* __restrict__ b0c,
    float* __restrict__ uv, const float* __restrict__ iv,
    float* __restrict__ W, float* __restrict__ out)
{
    const int b = blockIdx.x;
    const int tid = threadIdx.x;
    if (b < 80) {
        const int c = tid;
        const int r0 = b * 4;
        const float* Ar = A + (size_t)r0 * NP;
        float a0 = 0.f, a1 = 0.f, a2 = 0.f, a3 = 0.f;
        #pragma unroll 8
        for (int k = 0; k < NP; ++k) {
            const float bb = A[(size_t)k * NP + c];
            a0 = fmaf(Ar[k], bb, a0);
            a1 = fmaf(Ar[NP + k], bb, a1);
            a2 = fmaf(Ar[2 * NP + k], bb, a2);
            a3 = fmaf(Ar[3 * NP + k], bb, a3);
        }
        C[(size_t)r0 * NP + c] = a0;
        C[(size_t)(r0 + 1) * NP + c] = a1;
        C[(size_t)(r0 + 2) * NP + c] = a2;
        C[(size_t)(r0 + 3) * NP + c] = a3;
        return;
    }
    __shared__ float ysB[NP], ysC[NP];
    const float s = DTH / 8.0f;
    const float b0 = b0c[tid];
    const float cc = b0c[NP + tid];
    ysB[tid] = b0; ysC[tid] = cc;
    __syncthreads();

    float mb, mc, m2b, m2c, m3b, m3c;
    {
        float aB = 0.f, aC = 0.f;
        #pragma unroll 8
        for (int k = 0; k < NP; ++k) {
            const float a = MT[(size_t)k * NP + tid];
            aB = fmaf(a, ysB[k], aB);
            aC = fmaf(a, ysC[k], aC);
        }
        mb = aB; mc = aC;
    }
    __syncthreads(); ysB[tid] = mb; ysC[tid] = mc; __syncthreads();
    {
        float aB = 0.f, aC = 0.f;
        #pragma unroll 8
        for (int k = 0; k < NP; ++k) {
            const float a = MT[(size_t)k * NP + tid];
            aB = fmaf(a, ysB[k], aB);
            aC = fmaf(a, ysC[k], aC);
        }
        m2b = aB; m2c = aC;
    }
    __syncthreads(); ysB[tid] = m2b; ysC[tid] = m2c; __syncthreads();
    {
        float aB = 0.f, aC = 0.f;
        #pragma unroll 8
        for (int k = 0; k < NP; ++k) {
            const float a = MT[(size_t)k * NP + tid];
            aB = fmaf(a, ysB[k], aB);
            aC = fmaf(a, ysC[k], aC);
        }
        m3b = aB; m3c = aC;
    }

    const float u1 = s * (b0 + mb + (1.0f / 3.0f) * (m2b + m3b));
    const float u2 = s * (3.0f * b0 + 2.0f * mb + m2b);
    const float u3 = s * (3.0f * b0 + mb);
    const float u4 = s * b0;
    const float dd = s * (8.0f * cc + 4.0f * mc + (4.0f / 3.0f) * m2c + (1.0f / 3.0f) * m3c);

    uv[tid]          = u1;
    uv[NP + tid]     = u2;
    uv[2 * NP + tid] = u3;
    uv[3 * NP + tid] = u4;
    uv[4 * NP + tid] = dd;

    W[(size_t)(0 << 7) * NP + tid] = dd;
    W[(size_t)(1 << 7) * NP + tid] = u1;
    W[(size_t)(2 << 7) * NP + tid] = u2;
    W[(size_t)(3 << 7) * NP + tid] = u3;
    W[(size_t)(4 << 7) * NP + tid] = u4;

    if (tid < NN) out[tid] = iv[tid];
}

// P = M2 @ (M/6 + M2/24) + (I + M + M2/2); also PT0 = P^T.
__global__ void matmulP(const float* __restrict__ M2, const float* __restrict__ M,
                        float* __restrict__ P, float* __restrict__ PT0)
{
    const int c = blockIdx.x * 64 + threadIdx.x;
    const int r0 = blockIdx.y * 4;
    const float* Ar = M2 + (size_t)r0 * NP;
    float a0 = 0.f, a1 = 0.f, a2 = 0.f, a3 = 0.f;
    #pragma unroll 8
    for (int k = 0; k < NP; ++k) {
        const size_t o = (size_t)k * NP + c;
        const float b = (1.0f / 6.0f) * M[o] + (1.0f / 24.0f) * M2[o];
        a0 = fmaf(Ar[k], b, a0);
        a1 = fmaf(Ar[NP + k], b, a1);
        a2 = fmaf(Ar[2 * NP + k], b, a2);
        a3 = fmaf(Ar[3 * NP + k], b, a3);
    }
    float acc[4] = {a0, a1, a2, a3};
    float4 t;
    #pragma unroll
    for (int u = 0; u < 4; ++u) {
        const int r = r0 + u;
        const size_t idx = (size_t)r * NP + c;
        float v = acc[u] + M[idx] + 0.5f * M2[idx];
        if (r == c && r < NN) v += 1.0f;
        P[idx] = v;
        ((float*)&t)[u] = v;
    }
    *(float4*)(PT0 + (size_t)c * NP + r0) = t;
}

// ---------------------------------------------------------------------------
// Fat ladder kernel (unchanged from r14).
__global__ __launch_bounds__(320) void fat_kernel(
    const float* __restrict__ src, float* __restrict__ dst,
    float* __restrict__ PTall, int j, float* __restrict__ W,
    const float* __restrict__ Sin, float* __restrict__ Sout, int npairs)
{
    const int b = blockIdx.x;
    const int tid = threadIdx.x;
    if (b < 320) {
        const int w = tid >> 6, l = tid & 63;
        const int r = (b & 63) * 5 + w;
        const int c = (b >> 6) * 64 + l;
        const float* Ar = src + (size_t)r * NP;
        float c0 = 0.f, c1 = 0.f, c2 = 0.f, c3 = 0.f;
        #pragma unroll 4
        for (int k = 0; k < NP; k += 4) {
            c0 = fmaf(Ar[k],     src[(size_t)k * NP + c],       c0);
            c1 = fmaf(Ar[k + 1], src[(size_t)(k + 1) * NP + c], c1);
            c2 = fmaf(Ar[k + 2], src[(size_t)(k + 2) * NP + c], c2);
            c3 = fmaf(Ar[k + 3], src[(size_t)(k + 3) * NP + c], c3);
        }
        const float acc = (c0 + c1) + (c2 + c3);
        dst[(size_t)r * NP + c] = acc;
        PTall[(size_t)(j + 1) * NP * NP + (size_t)c * NP + r] = acc;
        return;
    }
    const float* PTj = PTall + (size_t)j * NP * NP;
    const int c0 = (b - 320) * 4;
    __shared__ float ys[4][NP];
    if (j < 7) {
        const int nc = 5 << j;
        #pragma unroll
        for (int u = 0; u < 4; ++u) {
            const int ci = c0 + u;
            float val = 0.0f;
            if (ci < nc) {
                const int v = ci >> j, mo = ci & ((1 << j) - 1);
                val = W[(size_t)((v << 7) + mo) * NP + tid];
            }
            ys[u][tid] = val;
        }
        __syncthreads();
        float a0 = 0.f, a1 = 0.f, a2 = 0.f, a3 = 0.f;
        #pragma unroll 8
        for (int k = 0; k < NP; ++k) {
            const float p = PTj[(size_t)k * NP + tid];
            a0 = fmaf(p, ys[0][k], a0);
            a1 = fmaf(p, ys[1][k], a1);
            a2 = fmaf(p, ys[2][k], a2);
            a3 = fmaf(p, ys[3][k], a3);
        }
        const float acc[4] = {a0, a1, a2, a3};
        #pragma unroll
        for (int u = 0; u < 4; ++u) {
            const int ci = c0 + u;
            if (ci < nc) {
                const int v = ci >> j, mo = ci & ((1 << j) - 1);
                W[(size_t)((v << 7) + (1 << j) + mo) * NP + tid] = acc[u];
            }
        }
    } else {
        #pragma unroll
        for (int u = 0; u < 4; ++u) {
            const int k = c0 + u;
            ys[u][tid] = (k < npairs) ? Sin[(size_t)(2 * k) * NP + tid] : 0.0f;
        }
        __syncthreads();
        float a0 = 0.f, a1 = 0.f, a2 = 0.f, a3 = 0.f;
        #pragma unroll 8
        for (int k = 0; k < NP; ++k) {
            const float p = PTj[(size_t)k * NP + tid];
            a0 = fmaf(p, ys[0][k], a0);
            a1 = fmaf(p, ys[1][k], a1);
            a2 = fmaf(p, ys[2][k], a2);
            a3 = fmaf(p, ys[3][k], a3);
        }
        const float acc[4] = {a0, a1, a2, a3};
        #pragma unroll
        for (int u = 0; u < 4; ++u) {
            const int k = c0 + u;
            if (k < npairs)
                Sout[(size_t)k * NP + tid] = acc[u] + Sin[(size_t)(2 * k + 1) * NP + tid];
        }
    }
}

// ---------------------------------------------------------------------------
// G_c for 4 consecutive c per block (W loads reused 4x).
__global__ void gsum_kernel(const float* __restrict__ W,
                            const float4* __restrict__ tau,
                            float* __restrict__ G)
{
    const int r = blockIdx.x * 64 + threadIdx.x;
    const int c0 = blockIdx.y * 4;
    const float* W0 = W;
    const float* W1 = W + 1 * (size_t)L_CHUNK * NP;
    const float* W2 = W + 2 * (size_t)L_CHUNK * NP;
    const float* W3 = W + 3 * (size_t)L_CHUNK * NP;
    const float* W4 = W + 4 * (size_t)L_CHUNK * NP;
    const int cc0 = (c0     < N_BND) ? c0     : N_BND - 1;
    const int cc1 = (c0 + 1 < N_BND) ? c0 + 1 : N_BND - 1;
    const int cc2 = (c0 + 2 < N_BND) ? c0 + 2 : N_BND - 1;
    const int cc3 = (c0 + 3 < N_BND) ? c0 + 3 : N_BND - 1;
    const int nb0 = cc0 * L_CHUNK + L_CHUNK - 1;
    const int nb1 = cc1 * L_CHUNK + L_CHUNK - 1;
    const int nb2 = cc2 * L_CHUNK + L_CHUNK - 1;
    const int nb3 = cc3 * L_CHUNK + L_CHUNK - 1;
    float g0 = 0.f, g1 = 0.f, g2 = 0.f, g3 = 0.f;
    #pragma unroll 2
    for (int m = 0; m < L_CHUNK; ++m) {
        const float4 a0 = tau[nb0 - m];
        const float4 a1 = tau[nb1 - m];
        const float4 a2 = tau[nb2 - m];
        const float4 a3 = tau[nb3 - m];
        const size_t o = (size_t)m * NP + r;
        const float w0 = W0[o], w1 = W1[o], w2 = W2[o], w3 = W3[o], w4 = W4[o];
        float t;
        t = w0; t = fmaf(a0.x, w1, t); t = fmaf(a0.y, w2, t);
        t = fmaf(a0.z, w3, t); t = fmaf(a0.w, w4, t); g0 += t;
        t = w0; t = fmaf(a1.x, w1, t); t = fmaf(a1.y, w2, t);
        t = fmaf(a1.z, w3, t); t = fmaf(a1.w, w4, t); g1 += t;
        t = w0; t = fmaf(a2.x, w1, t); t = fmaf(a2.y, w2, t);
        t = fmaf(a2.z, w3, t); t = fmaf(a2.w, w4, t); g2 += t;
        t = w0; t = fmaf(a3.x, w1, t); t = fmaf(a3.y, w2, t);
        t = fmaf(a3.z, w3, t); t = fmaf(a3.w, w4, t); g3 += t;
    }
    G[(size_t)(c0    ) * NP + r] = (c0     < N_BND) ? g0 : 0.f;
    G[(size_t)(c0 + 1) * NP + r] = (c0 + 1 < N_BND) ? g1 : 0.f;
    G[(size_t)(c0 + 2) * NP + r] = (c0 + 2 < N_BND) ? g2 : 0.f;
    G[(size_t)(c0 + 3) * NP + r] = (c0 + 3 < N_BND) ? g3 : 0.f;
}

// ---------------------------------------------------------------------------
// 8-wave engine helpers (bscan/brefill).
__device__ __forceinline__ void load_pfrag(const float* __restrict__ Psrc,
                                           vf2 p[5][20], int l, int w)
{
    #pragma unroll
    for (int k = 0; k < 5; ++k) {
        const int row = (k < 4) ? (4 * l + k) : (256 + l);
        const float* Pr = Psrc + (size_t)row * NP + 40 * w;
        #pragma unroll
        for (int j4 = 0; j4 < 10; ++j4) {
            const float4 v4 = *(const float4*)(Pr + 4 * j4);
            vf2 a; a.x = v4.x; a.y = v4.y;
            vf2 b; b.x = v4.z; b.y = v4.w;
            p[k][2 * j4] = a;
            p[k][2 * j4 + 1] = b;
        }
    }
    #pragma unroll
    for (int k = 0; k < 5; ++k)
        #pragma unroll
        for (int jj = 0; jj < 20; jj += 4)
            PIN4(p[k][jj], p[k][jj + 1], p[k][jj + 2], p[k][jj + 3]);
}

__device__ __forceinline__ void fma_phase(const vf2 p[5][20],
                                          const float* __restrict__ yb,
                                          float* __restrict__ pw, int l)
{
    vf2 a0 = {0.f, 0.f}, a1 = {0.f, 0.f}, a2 = {0.f, 0.f},
        a3 = {0.f, 0.f}, a4 = {0.f, 0.f};
    #pragma unroll
    for (int j4 = 0; j4 < 10; ++j4) {
        const float4 yv = *(const float4*)(yb + 4 * j4);
        vf2 y01; y01.x = yv.x; y01.y = yv.y;
        vf2 y23; y23.x = yv.z; y23.y = yv.w;
        const int jj = 2 * j4;
        PKFMA(a0, p[0][jj], y01); PKFMA(a0, p[0][jj + 1], y23);
        PKFMA(a1, p[1][jj], y01); PKFMA(a1, p[1][jj + 1], y23);
        PKFMA(a2, p[2][jj], y01); PKFMA(a2, p[2][jj + 1], y23);
        PKFMA(a3, p[3][jj], y01); PKFMA(a3, p[3][jj + 1], y23);
        PKFMA(a4, p[4][jj], y01); PKFMA(a4, p[4][jj + 1], y23);
    }
    float4 h4;
    h4.x = a0.x + a0.y;
    h4.y = a1.x + a1.y;
    h4.z = a2.x + a2.y;
    h4.w = a3.x + a3.y;
    *(float4*)(pw + 4 * l) = h4;          // rows 4l..4l+3 (16B aligned)
    pw[256 + l] = a4.x + a4.y;            // row 256+l
}

__device__ __forceinline__ float reduce8(const float* __restrict__ pb, int r)
{
    float s = pb[r];
    #pragma unroll
    for (int k = 1; k < 8; ++k) s += pb[k * NP + r];
    return s;
}

// ---------------------------------------------------------------------------
// 16-wave engine helpers (refill).  Wave w owns cols [20w, 20w+20); lane l
// accumulators: rows {4l+k, k<4} and {256+l}.  P = 100 floats/thread.
__device__ __forceinline__ void load_pfrag16(const float* __restrict__ Psrc,
                                             vf2 p[5][10], int l, int w)
{
    #pragma unroll
    for (int k = 0; k < 5; ++k) {
        const int row = (k < 4) ? (4 * l + k) : (256 + l);
        const float* Pr = Psrc + (size_t)row * NP + 20 * w;
        #pragma unroll
        for (int j4 = 0; j4 < 5; ++j4) {
            const float4 v4 = *(const float4*)(Pr + 4 * j4);
            vf2 a; a.x = v4.x; a.y = v4.y;
            vf2 b; b.x = v4.z; b.y = v4.w;
            p[k][2 * j4] = a;
            p[k][2 * j4 + 1] = b;
        }
    }
    #pragma unroll
    for (int k = 0; k < 5; ++k) {
        PIN4(p[k][0], p[k][1], p[k][2], p[k][3]);
        PIN4(p[k][4], p[k][5], p[k][6], p[k][7]);
        PIN2(p[k][8], p[k][9]);
    }
}

__device__ __forceinline__ void fma_phase16(const vf2 p[5][10],
                                            const float* __restrict__ yb,
                                            float* __restrict__ pw, int l)
{
    vf2 a0 = {0.f, 0.f}, a1 = {0.f, 0.f}, a2 = {0.f, 0.f},
        a3 = {0.f, 0.f}, a4 = {0.f, 0.f};
    #pragma unroll
    for (int j4 = 0; j4 < 5; ++j4) {
        const float4 yv = *(const float4*)(yb + 4 * j4);
        vf2 y01; y01.x = yv.x; y01.y = yv.y;
        vf2 y23; y23.x = yv.z; y23.y = yv.w;
        const int jj = 2 * j4;
        PKFMA(a0, p[0][jj], y01); PKFMA(a0, p[0][jj + 1], y23);
        PKFMA(a1, p[1][jj], y01); PKFMA(a1, p[1][jj + 1], y23);
        PKFMA(a2, p[2][jj], y01); PKFMA(a2, p[2][jj + 1], y23);
        PKFMA(a3, p[3][jj], y01); PKFMA(a3, p[3][jj + 1], y23);
        PKFMA(a4, p[4][jj], y01); PKFMA(a4, p[4][jj + 1], y23);
    }
    float4 h4;
    h4.x = a0.x + a0.y;
    h4.y = a1.x + a1.y;
    h4.z = a2.x + a2.y;
    h4.w = a3.x + a3.y;
    *(float4*)(pw + 4 * l) = h4;          // rows 4l..4l+3
    pw[256 + l] = a4.x + a4.y;            // row 256+l
}

__device__ __forceinline__ float reduce16(const float* __restrict__ pb, int r)
{
    float s = pb[r];
    #pragma unroll
    for (int k = 1; k < 16; ++k) s += pb[k * NP + r];
    return s;
}

// ---------------------------------------------------------------------------
// Level-2 boundary: Z_{g+1} = P^2048 Z_g + S4_g.  1 WG x 512, 29 steps.
__global__ ENGINE_LO void bscan_kernel(
    const float* __restrict__ PK, const float* __restrict__ S4,
    const float* __restrict__ iv, float* __restrict__ Z)
{
    const int tid = threadIdx.x;
    const int w = tid >> 6, l = tid & 63;
    vf2 p[5][20];
    load_pfrag(PK, p, l, w);

    __shared__ float ybuf[NP];
    __shared__ float part[2 * 8 * NP];
    __shared__ float ring[NSCAN * NP];

    const int r = 40 * w + l;   // valid when l < 40
    if (tid < NP) {
        const float y0 = (tid < NN) ? iv[tid] : 0.f;
        ybuf[tid] = y0;
        Z[tid] = y0;
    }
    float sv = (l < 40) ? S4[r] : 0.f;
    __syncthreads();

    for (int g = 0; g < NSCAN; ++g) {
        float* pb = part + (g & 1) * 8 * NP;
        fma_phase(p, ybuf + 40 * w, pb + w * NP, l);
        const float svn = (l < 40 && g + 1 < NSCAN)
                        ? S4[(size_t)(g + 1) * NP + r] : 0.f;
        __syncthreads();
        if (l < 40) {
            const float yn = reduce8(pb, r) + sv;
            ybuf[r] = yn;
            ring[g * NP + r] = yn;
        }
        sv = svn;
    }
    __syncthreads();
    for (int s2 = 0; s2 < NSCAN; ++s2)
        for (int j = tid; j < NP; j += 512)
            Z[(size_t)(s2 + 1) * NP + j] = ring[s2 * NP + j];
}

// ---------------------------------------------------------------------------
// Level-2 refill: Y_{16g+i+1} = P^128 Y_{16g+i} + G_{16g+i}.  30 WGs x 512.
__global__ ENGINE_LO void brefill_kernel(
    const float* __restrict__ PL, const float* __restrict__ G,
    const float* __restrict__ Z, float* __restrict__ Y)
{
    const int tid = threadIdx.x;
    const int w = tid >> 6, l = tid & 63;
    vf2 p[5][20];
    load_pfrag(PL, p, l, w);

    __shared__ float ybuf[NP];
    __shared__ float part[2 * 8 * NP];
    __shared__ float ring[16 * NP];

    const int g = blockIdx.x;
    const int nsteps = (16 * g + 16 <= N_BND) ? 16 : (N_BND - 16 * g);
    const int r = 40 * w + l;
    if (tid < NP) {
        const float z = Z[(size_t)g * NP + tid];
        ybuf[tid] = z;
        if (g == 0) Y[tid] = z;
    }
    float gv = (l < 40) ? G[(size_t)(16 * g) * NP + r] : 0.f;
    __syncthreads();

    for (int i = 0; i < nsteps; ++i) {
        float* pb = part + (i & 1) * 8 * NP;
        fma_phase(p, ybuf + 40 * w, pb + w * NP, l);
        const float gvn = (l < 40 && i + 1 < nsteps)
                        ? G[(size_t)(16 * g + i + 1) * NP + r] : 0.f;
        __syncthreads();
        if (l < 40) {
            const float yn = reduce8(pb, r) + gv;
            ybuf[r] = yn;
            ring[i * NP + r] = yn;
        }
        gv = gvn;
    }
    __syncthreads();
    for (int s2 = 0; s2 < nsteps; ++s2)
        for (int j = tid; j < NP; j += 512)
            Y[(size_t)(16 * g + 1 + s2) * NP + j] = ring[s2 * NP + j];
}

// ---------------------------------------------------------------------------
// Level-1 refill, r15: 235 WGs x 1024 (16 waves); WG b advances TWO chains
// (chunks 2b, 2b+1) half a step apart:
//   phase1: flushA? ; fmaA(i) ; reduceB(i-1)   -> barrier
//   phase2: flushB? ; fmaB(i) ; reduceA(i)     -> barrier
// Reduce done by threads tid<320 (row = tid, 16-way sum, coalesced).
// LDS = 64,256 B (just under the 64 KB static cap).
__global__ ENGINE16 void refill_kernel(
    const float* __restrict__ P, const float* __restrict__ uv,
    const float4* __restrict__ tau, const float* __restrict__ Y,
    float* __restrict__ out)
{
    const int tid = threadIdx.x;
    const int w = tid >> 6, l = tid & 63;
    vf2 p[5][10];
    load_pfrag16(P, p, l, w);

    __shared__ float ybufA[NP], ybufB[NP];
    __shared__ __align__(16) float partA[16 * NP], partB[16 * NP];
    __shared__ float ringA[8 * NP], ringB[8 * NP];
    __shared__ float4 tausA[8], tausB[8];

    float du0 = 0.f, du1 = 0.f, du2 = 0.f, du3 = 0.f, dd = 0.f;
    if (tid < NP) {
        du0 = uv[tid]; du1 = uv[NP + tid]; du2 = uv[2 * NP + tid];
        du3 = uv[3 * NP + tid]; dd = uv[4 * NP + tid];
    }

    const int b = blockIdx.x;
    const int cA = 2 * b, cB = 2 * b + 1;
    const int n0A = cA * L_CHUNK;
    const int n0B = cB * L_CHUNK;
    const int nA = (n0A + L_CHUNK < TS) ? L_CHUNK : (TS - n0A);
    const bool hasB = (cB < N_CHUNK);   // when true, nB == nA == 128

    if (tid < NP) {
        ybufA[tid] = Y[(size_t)cA * NP + tid];
        if (hasB) ybufB[tid] = Y[(size_t)cB * NP + tid];
    }
    if (tid < 8) {
        if (tid < nA) tausA[tid] = tau[n0A + tid];
        if (hasB) tausB[tid] = tau[n0B + tid];
    }
    int wsA = 0, wsB = 0;
    __syncthreads();

    for (int i = 0; i < nA; ++i) {
        // ---------------- phase 1: flushA? ; fmaA(i) ; reduceB(i-1)
        if (i - wsA == 8) {
            #pragma unroll 1
            for (int s2 = 0; s2 < 8; ++s2) {
                const size_t row = (size_t)(n0A + wsA + 1 + s2);
                for (int j = tid; j < NN; j += 1024)
                    out[row * NN + j] = ringA[s2 * NP + j];
            }
            wsA = i;
            if (tid < 8 && i + tid < nA) tausA[tid] = tau[n0A + i + tid];
        }
        fma_phase16(p, ybufA + 20 * w, partA + w * NP, l);
        if (hasB && i > 0 && tid < NP) {
            const int sb = (i - 1) - wsB;
            const float4 a = tausB[sb];
            float yn = reduce16(partB, tid) + dd;
            yn = fmaf(a.x, du0, yn);
            yn = fmaf(a.y, du1, yn);
            yn = fmaf(a.z, du2, yn);
            yn = fmaf(a.w, du3, yn);
            ybufB[tid] = yn;
            ringB[sb * NP + tid] = yn;
        }
        __syncthreads();
        // ---------------- phase 2: flushB? ; fmaB(i) ; reduceA(i)
        if (hasB && i - wsB == 8) {
            #pragma unroll 1
            for (int s2 = 0; s2 < 8; ++s2) {
                const size_t row = (size_t)(n0B + wsB + 1 + s2);
                for (int j = tid; j < NN; j += 1024)
                    out[row * NN + j] = ringB[s2 * NP + j];
            }
            wsB = i;
            if (tid < 8) tausB[tid] = tau[n0B + i + tid];
        }
        if (hasB) fma_phase16(p, ybufB + 20 * w, partB + w * NP, l);
        if (tid < NP) {
            const int sa = i - wsA;
            const float4 a = tausA[sa];
            float yn = reduce16(partA, tid) + dd;
            yn = fmaf(a.x, du0, yn);
            yn = fmaf(a.y, du1, yn);
            yn = fmaf(a.z, du2, yn);
            yn = fmaf(a.w, du3, yn);
            ybufA[tid] = yn;
            ringA[sa * NP + tid] = yn;
        }
        __syncthreads();
    }

    // post-loop: reduceB(nA-1), then tail flushes
    if (hasB && tid < NP) {
        const int sb = (nA - 1) - wsB;
        const float4 a = tausB[sb];
        float yn = reduce16(partB, tid) + dd;
        yn = fmaf(a.x, du0, yn);
        yn = fmaf(a.y, du1, yn);
        yn = fmaf(a.z, du2, yn);
        yn = fmaf(a.w, du3, yn);
        ringB[sb * NP + tid] = yn;
    }
    __syncthreads();
    {
        const int cntA = nA - wsA;
        for (int s2 = 0; s2 < cntA; ++s2) {
            const size_t row = (size_t)(n0A + wsA + 1 + s2);
            for (int j = tid; j < NN; j += 1024)
                out[row * NN + j] = ringA[s2 * NP + j];
        }
        if (hasB) {
            const int cntB = nA - wsB;
            for (int s2 = 0; s2 < cntB; ++s2) {
                const size_t row = (size_t)(n0B + wsB + 1 + s2);
                for (int j = tid; j < NN; j += 1024)
                    out[row * NN + j] = ringB[s2 * NP + j];
            }
        }
    }
}

// ---------------------------------------------------------------------------
extern "C" void kernel_launch(void* const* d_in, const int* in_sizes, int n_in,
                              void* d_out, int out_size, void* d_ws, size_t ws_size,
                              hipStream_t stream)
{
    const float* params = (const float*)d_in[0];
    const float* tlo    = (const float*)d_in[1];
    const float* thi    = (const float*)d_in[2];
    const float* B      = (const float*)d_in[3];
    const float* tout_t = (const float*)d_in[4];
    const float* tout_v = (const float*)d_in[5];
    const float* iv     = (const float*)d_in[6];
    const int*   t0     = (const int*)d_in[8];
    float* out = (float*)d_out;
    float* ws  = (float*)d_ws;

    float*  M    = ws + WS_M;
    float*  MT   = ws + WS_MT;
    float*  M2   = ws + WS_M2;
    float*  P    = ws + WS_P;
    float*  UV   = ws + WS_UV;
    float*  B0C  = ws + WS_B0C;
    float4* TAU  = (float4*)(ws + WS_TAU);
    float*  W    = ws + WS_W;
    float*  G    = ws + WS_G;
    float*  Y    = ws + WS_Y;
    float*  Z    = ws + WS_Z;
    float*  SA   = ws + WS_SA;
    float*  SB   = ws + WS_SB;
    float*  PL   = ws + WS_PL;
    float*  PA   = ws + WS_PA;
    float*  PB   = ws + WS_PB;
    float*  PT   = ws + WS_PT;     // slot j: transpose of P^(2^j)

    // Phase A (fused): buildrow + b0c + tau in one launch
    phaseA_kernel<<<619, 320, 0, stream>>>(params, tlo, thi, B, tout_t,
                                           tout_v, t0, M, MT, B0C, TAU);

    // M2 = M@M fused with vec (forcing vectors, W seed, out row 0)
    mm4r_vec_kernel<<<81, 320, 0, stream>>>(M, M2, MT, B0C, UV, iv, W, out);

    // P = M2@(M/6+M2/24) + I + M + M2/2 (+ PT[0])
    matmulP<<<dim3(5, 80), 64, 0, stream>>>(M2, M, P, PT);

    // Squaring ladder with riders.
    // j=0..6: W doubling riders; dst of j=6 is PL = P^128.
    const float* src = P;
    for (int j = 0; j < 7; ++j) {
        float* dst = (j == 6) ? PL : ((j & 1) ? PB : PA);
        const int aux = ((5 << j) + 3) / 4;
        fat_kernel<<<320 + aux, 320, 0, stream>>>(src, dst, PT, j, W,
                                                  nullptr, nullptr, 0);
        src = dst;
    }
    // Boundary forcing sums over each 128-step chunk (4 c's per block).
    gsum_kernel<<<dim3(5, NB_PAD / 4), 64, 0, stream>>>(W, TAU, G);
    // j=7..10: pair-combine riders 480 -> 240 -> 120 -> 60 -> 30 group sums.
    const float* Spp[5] = { G, SA, SB, SA, SB };
    for (int j = 7; j < 11; ++j) {
        float* dst = (j & 1) ? PB : PA;
        const int npairs = 30720 >> j;     // 240, 120, 60, 30
        const int aux = (npairs + 3) / 4;
        fat_kernel<<<320 + aux, 320, 0, stream>>>(src, dst, PT, j, W,
                                                  Spp[j - 7], (float*)Spp[j - 6], npairs);
        src = dst;
    }
    // src == PA == P^2048; SB holds 30 group sums

    // Level-2 boundary chain + level-2 refill of Y
    bscan_kernel<<<1, 512, 0, stream>>>(PA, SB, iv, Z);
    brefill_kernel<<<N_GRP, 512, 0, stream>>>(PL, G, Z, Y);

    // Level-1 parallel refill (2 chains per WG, 16-wave engine)
    refill_kernel<<<N_WG2, 1024, 0, stream>>>(P, UV, TAU, Y, out);
}

// Round 9
// 707.771 us; speedup vs baseline: 1.3530x; 1.3530x over previous
//
#include <hip/hip_runtime.h>
#include <math.h>

// Problem constants
#define NN     302      // state dim (N_ROOMS + 2)
#define MM     301      // input dim (N_ROOMS + 1)
#define NROOMS 300
#define NP     320      // padded dim
#define TS     59999    // number of steps
#define KN     2001     // tout knots
#define DTH    30.0f

// Time-chunking (L_CHUNK=128; two chains per WG share one register-resident
// P copy — r10/r15: any config that shrinks the per-wave register budget
// below P's footprint forces L2 remat of P every step and is 2-11x slower.
// 8-wave ENGINE_LO (VGPR 124 + AGPR via gfx950 unified file) is the proven
// config: 274us refill.)
#define L_CHUNK 128     // steps per chunk (level 1)
#define N_CHUNK 469     // ceil(59999/128) chunks
#define N_WG2   235     // refill WGs (2 chains each)
#define N_BND   468     // boundary steps
#define NB_PAD  480     // padded boundary count (30 groups of 16)
#define N_GRP   30      // level-2 groups
#define NSCAN   29      // level-2 boundary-chain steps

// Workspace layout (in floats)
#define WS_M    0        // 102400
#define WS_M2   102400   // 102400
#define WS_P    204800   // 102400
#define WS_UV   307200   // 1600
#define WS_B0C  308800   // 640
#define WS_TAU  309440   // 240000 (float4 x 59999)
#define WS_W    549440   // 5 x 128 x 320 = 204800
#define WS_G    754240   // 480 x 320 = 153600
#define WS_Y    907840   // 469 x 320 = 150080
#define WS_Z    1057920  // 30 x 320 = 9600
#define WS_SA   1067520  // 240 x 320 = 76800
#define WS_SB   1144320  // 120 x 320 = 38400
#define WS_PL   1182720  // 102400  P^128 row-major
#define WS_PA   1285120  // 102400  ladder ping
#define WS_PB   1387520  // 102400  ladder pong
#define WS_PT   1489920  // 12 x 102400 (transposed powers, slot j = (P^(2^j))^T)
#define WS_MT   2718720  // 102400  M^T
                         // total 2821120 floats = 11.28 MB

typedef float vf2 __attribute__((ext_vector_type(2)));

// 512-thread engine: 8 waves; wave w owns cols [40w,40w+40) of P; lane l's
// accumulators cover rows {4l+k, k<4} and {256+l} (partial writes are
// 1 x ds_write_b128 + 1 x b32).  y broadcast via LDS ybuf.
#define ENGINE_LO __launch_bounds__(512) __attribute__((amdgpu_waves_per_eu(2, 2)))
#define PKFMA(acc, a, b) asm("v_pk_fma_f32 %0, %1, %2, %0" : "+v"(acc) : "v"(a), "v"(b))
#define PIN4(a, b, c, d) asm volatile("" : "+v"(a), "+v"(b), "+v"(c), "+v"(d))

// ---------------------------------------------------------------------------
// Phase-A mega-kernel: blocks 0..319 buildrow; 320..383 b0c (5 rows/block);
// 384..618 tau.  All independent — one launch, whole-GPU utilization.
__global__ __launch_bounds__(320) void phaseA_kernel(
    const float* __restrict__ params, const float* __restrict__ tlo,
    const float* __restrict__ thi, const float* __restrict__ B,
    const float* __restrict__ tout_t, const float* __restrict__ tout_v,
    const int* __restrict__ t0p,
    float* __restrict__ M, float* __restrict__ MT,
    float* __restrict__ b0c, float4* __restrict__ tau)
{
    __shared__ float red[5];
    __shared__ float Qs[NROOMS];
    const int b = blockIdx.x;
    const int tid = threadIdx.x;

    if (b < 320) {
        const int r = b;
        const int c = tid;
        float wv = 0.0f;
        if (r < NN && c < NN) {
            const int idx = r * NN + c;
            const float x = 1.0f / (1.0f + expf(-params[idx]));
            wv = tlo[idx] + (thi[idx] - tlo[idx]) * x;
        }
        float s = fabsf(wv);
        #pragma unroll
        for (int off = 32; off > 0; off >>= 1) s += __shfl_xor(s, off, 64);
        if ((c & 63) == 0) red[c >> 6] = s;
        __syncthreads();
        const float rs = red[0] + red[1] + red[2] + red[3] + red[4];
        float v = DTH * wv;
        if (r == c) v -= DTH * rs;
        M[r * NP + c] = v;
        MT[(size_t)c * NP + r] = v;
    } else if (b < 384) {
        for (int q = tid; q < NROOMS; q += 320) {
            const int idx = NN * NN + q;
            const float x = 1.0f / (1.0f + expf(-params[idx]));
            Qs[q] = tlo[idx] + (thi[idx] - tlo[idx]) * x;
        }
        __syncthreads();
        const int w = tid >> 6, l = tid & 63;
        const int r = (b - 320) * 5 + w;
        if (r >= NN) {
            if (l == 0) { b0c[r] = 0.0f; b0c[NP + r] = 0.0f; }
            return;
        }
        float s = 0.0f;
        for (int q = l; q < NROOMS; q += 64) s = fmaf(B[r * MM + 1 + q], Qs[q], s);
        #pragma unroll
        for (int off = 32; off > 0; off >>= 1) s += __shfl_xor(s, off, 64);
        if (l == 0) { b0c[r] = B[r * MM]; b0c[NP + r] = s; }
    } else {
        if (tid >= 256) return;
        const int n = (b - 384) * 256 + tid;
        if (n >= TS) return;
        const float tbase = 30.0f * (float)n + (float)(*t0p);
        float r[4];
        #pragma unroll
        for (int st = 0; st < 4; ++st) {
            const float x = tbase + 10.0f * (float)st;
            float res;
            if (x <= tout_t[0])            res = tout_v[0];
            else if (x >= tout_t[KN - 1])  res = tout_v[KN - 1];
            else {
                int k = (int)(x * (1.0f / 900.0f));
                if (k > KN - 2) k = KN - 2;
                if (k < 0) k = 0;
                if (x < tout_t[k] && k > 0) --k;
                else if (x >= tout_t[k + 1] && k < KN - 2) ++k;
                const float tk = tout_t[k], tk1 = tout_t[k + 1];
                const float wgt = (x - tk) / (tk1 - tk);
                res = tout_v[k] + wgt * (tout_v[k + 1] - tout_v[k]);
            }
            r[st] = res;
        }
        tau[n] = make_float4(r[0], r[1], r[2], r[3]);
    }
}

// ---------------------------------------------------------------------------
// M2 = M@M: 320 blocks x 1 row (r16: was 80 blocks = 0.31/CU; now 1.25/CU,
// 4-acc chain split) fused with vec_kernel (block 320).
__global__ __launch_bounds__(320) void mm4r_vec_kernel(
    const float* __restrict__ A, float* __restrict__ C,
    const float* __restrict__ MT, const float* __restrict__ b0c,
    float* __restrict__ uv, const float* __restrict__ iv,
    float* __restrict__ W, float* __restrict__ out)
{
    const int b = blockIdx.x;
    const int tid = threadIdx.x;
    if (b < 320) {
        const int c = tid;
        const float* Ar = A + (size_t)b * NP;
        float a0 = 0.f, a1 = 0.f, a2 = 0.f, a3 = 0.f;
        #pragma unroll 4
        for (int k = 0; k < NP; k += 4) {
            a0 = fmaf(Ar[k],     A[(size_t)k * NP + c],       a0);
            a1 = fmaf(Ar[k + 1], A[(size_t)(k + 1) * NP + c], a1);
            a2 = fmaf(Ar[k + 2], A[(size_t)(k + 2) * NP + c], a2);
            a3 = fmaf(Ar[k + 3], A[(size_t)(k + 3) * NP + c], a3);
        }
        C[(size_t)b * NP + c] = (a0 + a1) + (a2 + a3);
        return;
    }
    // ---- vec body (block 320): forcing vectors via MT column-matvecs ----
    __shared__ float ysB[NP], ysC[NP];
    const float s = DTH / 8.0f;
    const float b0 = b0c[tid];
    const float cc = b0c[NP + tid];
    ysB[tid] = b0; ysC[tid] = cc;
    __syncthreads();

    float mb, mc, m2b, m2c, m3b, m3c;
    {
        float aB = 0.f, aC = 0.f;
        #pragma unroll 8
        for (int k = 0; k < NP; ++k) {
            const float a = MT[(size_t)k * NP + tid];
            aB = fmaf(a, ysB[k], aB);
            aC = fmaf(a, ysC[k], aC);
        }
        mb = aB; mc = aC;
    }
    __syncthreads(); ysB[tid] = mb; ysC[tid] = mc; __syncthreads();
    {
        float aB = 0.f, aC = 0.f;
        #pragma unroll 8
        for (int k = 0; k < NP; ++k) {
            const float a = MT[(size_t)k * NP + tid];
            aB = fmaf(a, ysB[k], aB);
            aC = fmaf(a, ysC[k], aC);
        }
        m2b = aB; m2c = aC;
    }
    __syncthreads(); ysB[tid] = m2b; ysC[tid] = m2c; __syncthreads();
    {
        float aB = 0.f, aC = 0.f;
        #pragma unroll 8
        for (int k = 0; k < NP; ++k) {
            const float a = MT[(size_t)k * NP + tid];
            aB = fmaf(a, ysB[k], aB);
            aC = fmaf(a, ysC[k], aC);
        }
        m3b = aB; m3c = aC;
    }

    const float u1 = s * (b0 + mb + (1.0f / 3.0f) * (m2b + m3b));
    const float u2 = s * (3.0f * b0 + 2.0f * mb + m2b);
    const float u3 = s * (3.0f * b0 + mb);
    const float u4 = s * b0;
    const float dd = s * (8.0f * cc + 4.0f * mc + (4.0f / 3.0f) * m2c + (1.0f / 3.0f) * m3c);

    uv[tid]          = u1;
    uv[NP + tid]     = u2;
    uv[2 * NP + tid] = u3;
    uv[3 * NP + tid] = u4;
    uv[4 * NP + tid] = dd;

    W[(size_t)(0 << 7) * NP + tid] = dd;
    W[(size_t)(1 << 7) * NP + tid] = u1;
    W[(size_t)(2 << 7) * NP + tid] = u2;
    W[(size_t)(3 << 7) * NP + tid] = u3;
    W[(size_t)(4 << 7) * NP + tid] = u4;

    if (tid < NN) out[tid] = iv[tid];
}

// P = M2 @ (M/6 + M2/24) + (I + M + M2/2); also PT0 = P^T.
// r16: 320 blocks x 320 threads, 1 row per block (was 1.56 blocks/CU @64thr).
__global__ __launch_bounds__(320) void matmulP(
    const float* __restrict__ M2, const float* __restrict__ M,
    float* __restrict__ P, float* __restrict__ PT0)
{
    const int c = threadIdx.x;
    const int r = blockIdx.x;
    const float* Ar = M2 + (size_t)r * NP;
    float a0 = 0.f, a1 = 0.f, a2 = 0.f, a3 = 0.f;
    #pragma unroll 4
    for (int k = 0; k < NP; k += 4) {
        const size_t o = (size_t)k * NP + c;
        a0 = fmaf(Ar[k],     (1.0f / 6.0f) * M[o]          + (1.0f / 24.0f) * M2[o],          a0);
        a1 = fmaf(Ar[k + 1], (1.0f / 6.0f) * M[o + NP]     + (1.0f / 24.0f) * M2[o + NP],     a1);
        a2 = fmaf(Ar[k + 2], (1.0f / 6.0f) * M[o + 2 * NP] + (1.0f / 24.0f) * M2[o + 2 * NP], a2);
        a3 = fmaf(Ar[k + 3], (1.0f / 6.0f) * M[o + 3 * NP] + (1.0f / 24.0f) * M2[o + 3 * NP], a3);
    }
    const size_t idx = (size_t)r * NP + c;
    float v = (a0 + a1) + (a2 + a3) + M[idx] + 0.5f * M2[idx];
    if (r == c && r < NN) v += 1.0f;
    P[idx] = v;
    PT0[(size_t)c * NP + r] = v;
}

// ---------------------------------------------------------------------------
// Fat ladder kernel.  r16 squaring: 640 blocks (b<640), k-split halves —
// block = (rgroup b&63 -> 5 rows, cgroup b>>6 -> 32 cols); threads tid<160
// compute k=[0,160), tid>=160 compute k=[160,320); combine via LDS.
// 2x block parallelism (2.5/CU) and half the FMA latency chain.
// Riders (b>=640): j<7 W doubling; j>=7 pair-combine (unchanged logic).
__global__ __launch_bounds__(320) void fat_kernel(
    const float* __restrict__ src, float* __restrict__ dst,
    float* __restrict__ PTall, int j, float* __restrict__ W,
    const float* __restrict__ Sin, float* __restrict__ Sout, int npairs)
{
    const int b = blockIdx.x;
    const int tid = threadIdx.x;
    if (b < 640) {
        __shared__ float psum[160];
        const int half = tid / 160;          // 0 or 1
        const int idx  = tid - half * 160;   // 0..159
        const int rr = idx >> 5;             // 0..4
        const int cc = idx & 31;             // 0..31
        const int r = (b & 63) * 5 + rr;
        const int c = (b >> 6) * 32 + cc;
        const float* Ar = src + (size_t)r * NP + 160 * half;
        const float* Bc = src + (size_t)(160 * half) * NP + c;
        float c0 = 0.f, c1 = 0.f, c2 = 0.f, c3 = 0.f;
        #pragma unroll 4
        for (int k = 0; k < 160; k += 4) {
            c0 = fmaf(Ar[k],     Bc[(size_t)k * NP],       c0);
            c1 = fmaf(Ar[k + 1], Bc[(size_t)(k + 1) * NP], c1);
            c2 = fmaf(Ar[k + 2], Bc[(size_t)(k + 2) * NP], c2);
            c3 = fmaf(Ar[k + 3], Bc[(size_t)(k + 3) * NP], c3);
        }
        const float part = (c0 + c1) + (c2 + c3);
        if (half == 1) psum[idx] = part;
        __syncthreads();
        if (half == 0) {
            const float acc = part + psum[idx];
            dst[(size_t)r * NP + c] = acc;
            PTall[(size_t)(j + 1) * NP * NP + (size_t)c * NP + r] = acc;
        }
        return;
    }
    const float* PTj = PTall + (size_t)j * NP * NP;
    const int c0 = (b - 640) * 4;
    __shared__ float ys[4][NP];
    if (j < 7) {
        const int nc = 5 << j;
        #pragma unroll
        for (int u = 0; u < 4; ++u) {
            const int ci = c0 + u;
            float val = 0.0f;
            if (ci < nc) {
                const int v = ci >> j, mo = ci & ((1 << j) - 1);
                val = W[(size_t)((v << 7) + mo) * NP + tid];
            }
            ys[u][tid] = val;
        }
        __syncthreads();
        float a0 = 0.f, a1 = 0.f, a2 = 0.f, a3 = 0.f;
        #pragma unroll 8
        for (int k = 0; k < NP; ++k) {
            const float p = PTj[(size_t)k * NP + tid];
            a0 = fmaf(p, ys[0][k], a0);
            a1 = fmaf(p, ys[1][k], a1);
            a2 = fmaf(p, ys[2][k], a2);
            a3 = fmaf(p, ys[3][k], a3);
        }
        const float acc[4] = {a0, a1, a2, a3};
        #pragma unroll
        for (int u = 0; u < 4; ++u) {
            const int ci = c0 + u;
            if (ci < nc) {
                const int v = ci >> j, mo = ci & ((1 << j) - 1);
                W[(size_t)((v << 7) + (1 << j) + mo) * NP + tid] = acc[u];
            }
        }
    } else {
        #pragma unroll
        for (int u = 0; u < 4; ++u) {
            const int k = c0 + u;
            ys[u][tid] = (k < npairs) ? Sin[(size_t)(2 * k) * NP + tid] : 0.0f;
        }
        __syncthreads();
        float a0 = 0.f, a1 = 0.f, a2 = 0.f, a3 = 0.f;
        #pragma unroll 8
        for (int k = 0; k < NP; ++k) {
            const float p = PTj[(size_t)k * NP + tid];
            a0 = fmaf(p, ys[0][k], a0);
            a1 = fmaf(p, ys[1][k], a1);
            a2 = fmaf(p, ys[2][k], a2);
            a3 = fmaf(p, ys[3][k], a3);
        }
        const float acc[4] = {a0, a1, a2, a3};
        #pragma unroll
        for (int u = 0; u < 4; ++u) {
            const int k = c0 + u;
            if (k < npairs)
                Sout[(size_t)k * NP + tid] = acc[u] + Sin[(size_t)(2 * k + 1) * NP + tid];
        }
    }
}

// ---------------------------------------------------------------------------
// G_c for 4 consecutive c per block (W loads reused 4x).
__global__ void gsum_kernel(const float* __restrict__ W,
                            const float4* __restrict__ tau,
                            float* __restrict__ G)
{
    const int r = blockIdx.x * 64 + threadIdx.x;
    const int c0 = blockIdx.y * 4;
    const float* W0 = W;
    const float* W1 = W + 1 * (size_t)L_CHUNK * NP;
    const float* W2 = W + 2 * (size_t)L_CHUNK * NP;
    const float* W3 = W + 3 * (size_t)L_CHUNK * NP;
    const float* W4 = W + 4 * (size_t)L_CHUNK * NP;
    const int cc0 = (c0     < N_BND) ? c0     : N_BND - 1;
    const int cc1 = (c0 + 1 < N_BND) ? c0 + 1 : N_BND - 1;
    const int cc2 = (c0 + 2 < N_BND) ? c0 + 2 : N_BND - 1;
    const int cc3 = (c0 + 3 < N_BND) ? c0 + 3 : N_BND - 1;
    const int nb0 = cc0 * L_CHUNK + L_CHUNK - 1;
    const int nb1 = cc1 * L_CHUNK + L_CHUNK - 1;
    const int nb2 = cc2 * L_CHUNK + L_CHUNK - 1;
    const int nb3 = cc3 * L_CHUNK + L_CHUNK - 1;
    float g0 = 0.f, g1 = 0.f, g2 = 0.f, g3 = 0.f;
    #pragma unroll 2
    for (int m = 0; m < L_CHUNK; ++m) {
        const float4 a0 = tau[nb0 - m];
        const float4 a1 = tau[nb1 - m];
        const float4 a2 = tau[nb2 - m];
        const float4 a3 = tau[nb3 - m];
        const size_t o = (size_t)m * NP + r;
        const float w0 = W0[o], w1 = W1[o], w2 = W2[o], w3 = W3[o], w4 = W4[o];
        float t;
        t = w0; t = fmaf(a0.x, w1, t); t = fmaf(a0.y, w2, t);
        t = fmaf(a0.z, w3, t); t = fmaf(a0.w, w4, t); g0 += t;
        t = w0; t = fmaf(a1.x, w1, t); t = fmaf(a1.y, w2, t);
        t = fmaf(a1.z, w3, t); t = fmaf(a1.w, w4, t); g1 += t;
        t = w0; t = fmaf(a2.x, w1, t); t = fmaf(a2.y, w2, t);
        t = fmaf(a2.z, w3, t); t = fmaf(a2.w, w4, t); g2 += t;
        t = w0; t = fmaf(a3.x, w1, t); t = fmaf(a3.y, w2, t);
        t = fmaf(a3.z, w3, t); t = fmaf(a3.w, w4, t); g3 += t;
    }
    G[(size_t)(c0    ) * NP + r] = (c0     < N_BND) ? g0 : 0.f;
    G[(size_t)(c0 + 1) * NP + r] = (c0 + 1 < N_BND) ? g1 : 0.f;
    G[(size_t)(c0 + 2) * NP + r] = (c0 + 2 < N_BND) ? g2 : 0.f;
    G[(size_t)(c0 + 3) * NP + r] = (c0 + 3 < N_BND) ? g3 : 0.f;
}

// ---------------------------------------------------------------------------
// Engine helpers (8-wave).
__device__ __forceinline__ void load_pfrag(const float* __restrict__ Psrc,
                                           vf2 p[5][20], int l, int w)
{
    #pragma unroll
    for (int k = 0; k < 5; ++k) {
        const int row = (k < 4) ? (4 * l + k) : (256 + l);
        const float* Pr = Psrc + (size_t)row * NP + 40 * w;
        #pragma unroll
        for (int j4 = 0; j4 < 10; ++j4) {
            const float4 v4 = *(const float4*)(Pr + 4 * j4);
            vf2 a; a.x = v4.x; a.y = v4.y;
            vf2 b; b.x = v4.z; b.y = v4.w;
            p[k][2 * j4] = a;
            p[k][2 * j4 + 1] = b;
        }
    }
    #pragma unroll
    for (int k = 0; k < 5; ++k)
        #pragma unroll
        for (int jj = 0; jj < 20; jj += 4)
            PIN4(p[k][jj], p[k][jj + 1], p[k][jj + 2], p[k][jj + 3]);
}

__device__ __forceinline__ void fma_phase(const vf2 p[5][20],
                                          const float* __restrict__ yb,
                                          float* __restrict__ pw, int l)
{
    vf2 a0 = {0.f, 0.f}, a1 = {0.f, 0.f}, a2 = {0.f, 0.f},
        a3 = {0.f, 0.f}, a4 = {0.f, 0.f};
    #pragma unroll
    for (int j4 = 0; j4 < 10; ++j4) {
        const float4 yv = *(const float4*)(yb + 4 * j4);
        vf2 y01; y01.x = yv.x; y01.y = yv.y;
        vf2 y23; y23.x = yv.z; y23.y = yv.w;
        const int jj = 2 * j4;
        PKFMA(a0, p[0][jj], y01); PKFMA(a0, p[0][jj + 1], y23);
        PKFMA(a1, p[1][jj], y01); PKFMA(a1, p[1][jj + 1], y23);
        PKFMA(a2, p[2][jj], y01); PKFMA(a2, p[2][jj + 1], y23);
        PKFMA(a3, p[3][jj], y01); PKFMA(a3, p[3][jj + 1], y23);
        PKFMA(a4, p[4][jj], y01); PKFMA(a4, p[4][jj + 1], y23);
    }
    float4 h4;
    h4.x = a0.x + a0.y;
    h4.y = a1.x + a1.y;
    h4.z = a2.x + a2.y;
    h4.w = a3.x + a3.y;
    *(float4*)(pw + 4 * l) = h4;          // rows 4l..4l+3 (16B aligned)
    pw[256 + l] = a4.x + a4.y;            // row 256+l
}

__device__ __forceinline__ float reduce8(const float* __restrict__ pb, int r)
{
    float s = pb[r];
    #pragma unroll
    for (int k = 1; k < 8; ++k) s += pb[k * NP + r];
    return s;
}

// ---------------------------------------------------------------------------
// Level-2 boundary: Z_{g+1} = P^2048 Z_g + S4_g.  1 WG x 512, 29 steps.
__global__ ENGINE_LO void bscan_kernel(
    const float* __restrict__ PK, const float* __restrict__ S4,
    const float* __restrict__ iv, float* __restrict__ Z)
{
    const int tid = threadIdx.x;
    const int w = tid >> 6, l = tid & 63;
    vf2 p[5][20];
    load_pfrag(PK, p, l, w);

    __shared__ float ybuf[NP];
    __shared__ float part[2 * 8 * NP];
    __shared__ float ring[NSCAN * NP];

    const int r = 40 * w + l;   // valid when l < 40
    if (tid < NP) {
        const float y0 = (tid < NN) ? iv[tid] : 0.f;
        ybuf[tid] = y0;
        Z[tid] = y0;
    }
    float sv = (l < 40) ? S4[r] : 0.f;
    __syncthreads();

    for (int g = 0; g < NSCAN; ++g) {
        float* pb = part + (g & 1) * 8 * NP;
        fma_phase(p, ybuf + 40 * w, pb + w * NP, l);
        const float svn = (l < 40 && g + 1 < NSCAN)
                        ? S4[(size_t)(g + 1) * NP + r] : 0.f;
        __syncthreads();
        if (l < 40) {
            const float yn = reduce8(pb, r) + sv;
            ybuf[r] = yn;
            ring[g * NP + r] = yn;
        }
        sv = svn;
    }
    __syncthreads();
    for (int s2 = 0; s2 < NSCAN; ++s2)
        for (int j = tid; j < NP; j += 512)
            Z[(size_t)(s2 + 1) * NP + j] = ring[s2 * NP + j];
}

// ---------------------------------------------------------------------------
// Level-2 refill: Y_{16g+i+1} = P^128 Y_{16g+i} + G_{16g+i}.  30 WGs x 512.
__global__ ENGINE_LO void brefill_kernel(
    const float* __restrict__ PL, const float* __restrict__ G,
    const float* __restrict__ Z, float* __restrict__ Y)
{
    const int tid = threadIdx.x;
    const int w = tid >> 6, l = tid & 63;
    vf2 p[5][20];
    load_pfrag(PL, p, l, w);

    __shared__ float ybuf[NP];
    __shared__ float part[2 * 8 * NP];
    __shared__ float ring[16 * NP];

    const int g = blockIdx.x;
    const int nsteps = (16 * g + 16 <= N_BND) ? 16 : (N_BND - 16 * g);
    const int r = 40 * w + l;
    if (tid < NP) {
        const float z = Z[(size_t)g * NP + tid];
        ybuf[tid] = z;
        if (g == 0) Y[tid] = z;
    }
    float gv = (l < 40) ? G[(size_t)(16 * g) * NP + r] : 0.f;
    __syncthreads();

    for (int i = 0; i < nsteps; ++i) {
        float* pb = part + (i & 1) * 8 * NP;
        fma_phase(p, ybuf + 40 * w, pb + w * NP, l);
        const float gvn = (l < 40 && i + 1 < nsteps)
                        ? G[(size_t)(16 * g + i + 1) * NP + r] : 0.f;
        __syncthreads();
        if (l < 40) {
            const float yn = reduce8(pb, r) + gv;
            ybuf[r] = yn;
            ring[i * NP + r] = yn;
        }
        gv = gvn;
    }
    __syncthreads();
    for (int s2 = 0; s2 < nsteps; ++s2)
        for (int j = tid; j < NP; j += 512)
            Y[(size_t)(16 * g + 1 + s2) * NP + j] = ring[s2 * NP + j];
}

// ---------------------------------------------------------------------------
// Level-1 refill (r11/r14 structure, proven 274us): 235 WGs x 512; WG b
// advances TWO chains (chunks 2b and 2b+1) half a step apart, sharing one
// register-resident P:
//   phase1: fmaA(i) + reduceB(i-1)  -> barrier
//   phase2: fmaB(i) + reduceA(i)    -> barrier
__global__ ENGINE_LO void refill_kernel(
    const float* __restrict__ P, const float* __restrict__ uv,
    const float4* __restrict__ tau, const float* __restrict__ Y,
    float* __restrict__ out)
{
    const int tid = threadIdx.x;
    const int w = tid >> 6, l = tid & 63;
    vf2 p[5][20];
    load_pfrag(P, p, l, w);

    __shared__ float ybufA[NP], ybufB[NP];
    __shared__ float partA[8 * NP], partB[8 * NP];
    __shared__ float ringA[8 * NP], ringB[8 * NP];
    __shared__ float4 tausA[8], tausB[8];

    const int r = 40 * w + l;
    float du0 = 0.f, du1 = 0.f, du2 = 0.f, du3 = 0.f, dd = 0.f;
    if (l < 40) {
        du0 = uv[r]; du1 = uv[NP + r]; du2 = uv[2 * NP + r];
        du3 = uv[3 * NP + r]; dd = uv[4 * NP + r];
    }

    const int b = blockIdx.x;
    const int cA = 2 * b, cB = 2 * b + 1;
    const int n0A = cA * L_CHUNK;
    const int n0B = cB * L_CHUNK;
    const int nA = (n0A + L_CHUNK < TS) ? L_CHUNK : (TS - n0A);
    const bool hasB = (cB < N_CHUNK);   // when true, nB == nA == 128

    if (tid < NP) {
        ybufA[tid] = Y[(size_t)cA * NP + tid];
        if (hasB) ybufB[tid] = Y[(size_t)cB * NP + tid];
    }
    if (tid < 8) {
        if (tid < nA) tausA[tid] = tau[n0A + tid];
        if (hasB) tausB[tid] = tau[n0B + tid];
    }
    int wsA = 0, wsB = 0;
    __syncthreads();

    for (int i = 0; i < nA; ++i) {
        // ---------------- phase 1: flushA? ; fmaA(i) ; reduceB(i-1)
        if (i - wsA == 8) {
            #pragma unroll 1
            for (int s2 = 0; s2 < 8; ++s2) {
                const size_t row = (size_t)(n0A + wsA + 1 + s2);
                for (int j = tid; j < NN; j += 512)
                    out[row * NN + j] = ringA[s2 * NP + j];
            }
            wsA = i;
            if (tid < 8 && i + tid < nA) tausA[tid] = tau[n0A + i + tid];
        }
        fma_phase(p, ybufA + 40 * w, partA + w * NP, l);
        if (hasB && i > 0) {
            const int sb = (i - 1) - wsB;
            const float4 a = tausB[sb];
            if (l < 40) {
                float yn = reduce8(partB, r) + dd;
                yn = fmaf(a.x, du0, yn);
                yn = fmaf(a.y, du1, yn);
                yn = fmaf(a.z, du2, yn);
                yn = fmaf(a.w, du3, yn);
                ybufB[r] = yn;
                ringB[sb * NP + r] = yn;
            }
        }
        __syncthreads();
        // ---------------- phase 2: flushB? ; fmaB(i) ; reduceA(i)
        if (hasB && i - wsB == 8) {
            #pragma unroll 1
            for (int s2 = 0; s2 < 8; ++s2) {
                const size_t row = (size_t)(n0B + wsB + 1 + s2);
                for (int j = tid; j < NN; j += 512)
                    out[row * NN + j] = ringB[s2 * NP + j];
            }
            wsB = i;
            if (tid < 8) tausB[tid] = tau[n0B + i + tid];
        }
        if (hasB) fma_phase(p, ybufB + 40 * w, partB + w * NP, l);
        {
            const int sa = i - wsA;
            const float4 a = tausA[sa];
            if (l < 40) {
                float yn = reduce8(partA, r) + dd;
                yn = fmaf(a.x, du0, yn);
                yn = fmaf(a.y, du1, yn);
                yn = fmaf(a.z, du2, yn);
                yn = fmaf(a.w, du3, yn);
                ybufA[r] = yn;
                ringA[sa * NP + r] = yn;
            }
        }
        __syncthreads();
    }

    // post-loop: reduceB(nA-1), then tail flushes
    if (hasB) {
        const int sb = (nA - 1) - wsB;
        const float4 a = tausB[sb];
        if (l < 40) {
            float yn = reduce8(partB, r) + dd;
            yn = fmaf(a.x, du0, yn);
            yn = fmaf(a.y, du1, yn);
            yn = fmaf(a.z, du2, yn);
            yn = fmaf(a.w, du3, yn);
            ringB[sb * NP + r] = yn;
        }
    }
    __syncthreads();
    {
        const int cntA = nA - wsA;
        for (int s2 = 0; s2 < cntA; ++s2) {
            const size_t row = (size_t)(n0A + wsA + 1 + s2);
            for (int j = tid; j < NN; j += 512)
                out[row * NN + j] = ringA[s2 * NP + j];
        }
        if (hasB) {
            const int cntB = nA - wsB;
            for (int s2 = 0; s2 < cntB; ++s2) {
                const size_t row = (size_t)(n0B + wsB + 1 + s2);
                for (int j = tid; j < NN; j += 512)
                    out[row * NN + j] = ringB[s2 * NP + j];
            }
        }
    }
}

// ---------------------------------------------------------------------------
extern "C" void kernel_launch(void* const* d_in, const int* in_sizes, int n_in,
                              void* d_out, int out_size, void* d_ws, size_t ws_size,
                              hipStream_t stream)
{
    const float* params = (const float*)d_in[0];
    const float* tlo    = (const float*)d_in[1];
    const float* thi    = (const float*)d_in[2];
    const float* B      = (const float*)d_in[3];
    const float* tout_t = (const float*)d_in[4];
    const float* tout_v = (const float*)d_in[5];
    const float* iv     = (const float*)d_in[6];
    const int*   t0     = (const int*)d_in[8];
    float* out = (float*)d_out;
    float* ws  = (float*)d_ws;

    float*  M    = ws + WS_M;
    float*  MT   = ws + WS_MT;
    float*  M2   = ws + WS_M2;
    float*  P    = ws + WS_P;
    float*  UV   = ws + WS_UV;
    float*  B0C  = ws + WS_B0C;
    float4* TAU  = (float4*)(ws + WS_TAU);
    float*  W    = ws + WS_W;
    float*  G    = ws + WS_G;
    float*  Y    = ws + WS_Y;
    float*  Z    = ws + WS_Z;
    float*  SA   = ws + WS_SA;
    float*  SB   = ws + WS_SB;
    float*  PL   = ws + WS_PL;
    float*  PA   = ws + WS_PA;
    float*  PB   = ws + WS_PB;
    float*  PT   = ws + WS_PT;     // slot j: transpose of P^(2^j)

    // Phase A (fused): buildrow + b0c + tau in one launch
    phaseA_kernel<<<619, 320, 0, stream>>>(params, tlo, thi, B, tout_t,
                                           tout_v, t0, M, MT, B0C, TAU);

    // M2 = M@M (320 blocks) fused with vec (block 320)
    mm4r_vec_kernel<<<321, 320, 0, stream>>>(M, M2, MT, B0C, UV, iv, W, out);

    // P = M2@(M/6+M2/24) + I + M + M2/2 (+ PT[0]); 320 blocks x 1 row
    matmulP<<<320, 320, 0, stream>>>(M2, M, P, PT);

    // Squaring ladder with riders.
    // j=0..6: W doubling riders; dst of j=6 is PL = P^128.
    const float* src = P;
    for (int j = 0; j < 7; ++j) {
        float* dst = (j == 6) ? PL : ((j & 1) ? PB : PA);
        const int aux = ((5 << j) + 3) / 4;
        fat_kernel<<<640 + aux, 320, 0, stream>>>(src, dst, PT, j, W,
                                                  nullptr, nullptr, 0);
        src = dst;
    }
    // Boundary forcing sums over each 128-step chunk (4 c's per block).
    gsum_kernel<<<dim3(5, NB_PAD / 4), 64, 0, stream>>>(W, TAU, G);
    // j=7..10: pair-combine riders 480 -> 240 -> 120 -> 60 -> 30 group sums.
    const float* Spp[5] = { G, SA, SB, SA, SB };
    for (int j = 7; j < 11; ++j) {
        float* dst = (j & 1) ? PB : PA;
        const int npairs = 30720 >> j;     // 240, 120, 60, 30
        const int aux = (npairs + 3) / 4;
        fat_kernel<<<640 + aux, 320, 0, stream>>>(src, dst, PT, j, W,
                                                  Spp[j - 7], (float*)Spp[j - 6], npairs);
        src = dst;
    }
    // src == PA == P^2048; SB holds 30 group sums

    // Level-2 boundary chain + level-2 refill of Y
    bscan_kernel<<<1, 512, 0, stream>>>(PA, SB, iv, Z);
    brefill_kernel<<<N_GRP, 512, 0, stream>>>(PL, G, Z, Y);

    // Level-1 parallel refill (2 chains per WG, 8-wave engine)
    refill_kernel<<<N_WG2, 512, 0, stream>>>(P, UV, TAU, Y, out);
}

// Round 10
// 688.540 us; speedup vs baseline: 1.3908x; 1.0279x over previous
//
#include <hip/hip_runtime.h>
#include <math.h>

// Problem constants
#define NN     302      // state dim (N_ROOMS + 2)
#define MM     301      // input dim (N_ROOMS + 1)
#define NROOMS 300
#define NP     320      // padded dim
#define TS     59999    // number of steps
#define KN     2001     // tout knots
#define DTH    30.0f

// Time-chunking (L_CHUNK=128; two chains per WG share one register-resident
// P copy — r10/r15: any config that shrinks the per-wave register budget
// below P's footprint forces L2 remat of P every step and is 2-11x slower.
// 8-wave ENGINE_LO is the proven config: ~274us refill.)
// r17 = r14 verbatim (measured optimum 690us).  r16's occupancy-vs-reuse
// perturbations (1-row matmul blocks, fat k-split) all regressed: for
// L2-resident panel matmuls, row-blocking reuse > block-count occupancy.
#define L_CHUNK 128     // steps per chunk (level 1)
#define N_CHUNK 469     // ceil(59999/128) chunks
#define N_WG2   235     // refill WGs (2 chains each)
#define N_BND   468     // boundary steps
#define NB_PAD  480     // padded boundary count (30 groups of 16)
#define N_GRP   30      // level-2 groups
#define NSCAN   29      // level-2 boundary-chain steps

// Workspace layout (in floats)
#define WS_M    0        // 102400
#define WS_M2   102400   // 102400
#define WS_P    204800   // 102400
#define WS_UV   307200   // 1600
#define WS_B0C  308800   // 640
#define WS_TAU  309440   // 240000 (float4 x 59999)
#define WS_W    549440   // 5 x 128 x 320 = 204800
#define WS_G    754240   // 480 x 320 = 153600
#define WS_Y    907840   // 469 x 320 = 150080
#define WS_Z    1057920  // 30 x 320 = 9600
#define WS_SA   1067520  // 240 x 320 = 76800
#define WS_SB   1144320  // 120 x 320 = 38400
#define WS_PL   1182720  // 102400  P^128 row-major
#define WS_PA   1285120  // 102400  ladder ping
#define WS_PB   1387520  // 102400  ladder pong
#define WS_PT   1489920  // 12 x 102400 (transposed powers, slot j = (P^(2^j))^T)
#define WS_MT   2718720  // 102400  M^T
                         // total 2821120 floats = 11.28 MB

typedef float vf2 __attribute__((ext_vector_type(2)));

// 512-thread engine: 8 waves; wave w owns cols [40w,40w+40) of P; lane l's
// accumulators cover rows {4l+k, k<4} and {256+l} (partial writes are
// 1 x ds_write_b128 + 1 x b32).  y broadcast via LDS ybuf.
#define ENGINE_LO __launch_bounds__(512) __attribute__((amdgpu_waves_per_eu(2, 2)))
#define PKFMA(acc, a, b) asm("v_pk_fma_f32 %0, %1, %2, %0" : "+v"(acc) : "v"(a), "v"(b))
#define PIN4(a, b, c, d) asm volatile("" : "+v"(a), "+v"(b), "+v"(c), "+v"(d))

// ---------------------------------------------------------------------------
// Phase-A mega-kernel: blocks 0..319 buildrow; 320..383 b0c (5 rows/block);
// 384..618 tau.  All independent — one launch, whole-GPU utilization.
__global__ __launch_bounds__(320) void phaseA_kernel(
    const float* __restrict__ params, const float* __restrict__ tlo,
    const float* __restrict__ thi, const float* __restrict__ B,
    const float* __restrict__ tout_t, const float* __restrict__ tout_v,
    const int* __restrict__ t0p,
    float* __restrict__ M, float* __restrict__ MT,
    float* __restrict__ b0c, float4* __restrict__ tau)
{
    __shared__ float red[5];
    __shared__ float Qs[NROOMS];
    const int b = blockIdx.x;
    const int tid = threadIdx.x;

    if (b < 320) {
        // ---- buildrow: M = DTH*W with diag -= DTH*sum|W[r,:]| ----
        const int r = b;
        const int c = tid;
        float wv = 0.0f;
        if (r < NN && c < NN) {
            const int idx = r * NN + c;
            const float x = 1.0f / (1.0f + expf(-params[idx]));
            wv = tlo[idx] + (thi[idx] - tlo[idx]) * x;
        }
        float s = fabsf(wv);
        #pragma unroll
        for (int off = 32; off > 0; off >>= 1) s += __shfl_xor(s, off, 64);
        if ((c & 63) == 0) red[c >> 6] = s;
        __syncthreads();
        const float rs = red[0] + red[1] + red[2] + red[3] + red[4];
        float v = DTH * wv;
        if (r == c) v -= DTH * rs;
        M[r * NP + c] = v;
        MT[(size_t)c * NP + r] = v;
    } else if (b < 384) {
        // ---- b0c: wave w of this block handles row r = (b-320)*5 + w ----
        for (int q = tid; q < NROOMS; q += 320) {
            const int idx = NN * NN + q;
            const float x = 1.0f / (1.0f + expf(-params[idx]));
            Qs[q] = tlo[idx] + (thi[idx] - tlo[idx]) * x;
        }
        __syncthreads();
        const int w = tid >> 6, l = tid & 63;
        const int r = (b - 320) * 5 + w;
        if (r >= NN) {
            if (l == 0) { b0c[r] = 0.0f; b0c[NP + r] = 0.0f; }
            return;
        }
        float s = 0.0f;
        for (int q = l; q < NROOMS; q += 64) s = fmaf(B[r * MM + 1 + q], Qs[q], s);
        #pragma unroll
        for (int off = 32; off > 0; off >>= 1) s += __shfl_xor(s, off, 64);
        if (l == 0) { b0c[r] = B[r * MM]; b0c[NP + r] = s; }
    } else {
        // ---- tau: per-step Tout interp coefficients (np.interp clone) ----
        if (tid >= 256) return;
        const int n = (b - 384) * 256 + tid;
        if (n >= TS) return;
        const float tbase = 30.0f * (float)n + (float)(*t0p);
        float r[4];
        #pragma unroll
        for (int st = 0; st < 4; ++st) {
            const float x = tbase + 10.0f * (float)st;
            float res;
            if (x <= tout_t[0])            res = tout_v[0];
            else if (x >= tout_t[KN - 1])  res = tout_v[KN - 1];
            else {
                int k = (int)(x * (1.0f / 900.0f));
                if (k > KN - 2) k = KN - 2;
                if (k < 0) k = 0;
                if (x < tout_t[k] && k > 0) --k;
                else if (x >= tout_t[k + 1] && k < KN - 2) ++k;
                const float tk = tout_t[k], tk1 = tout_t[k + 1];
                const float wgt = (x - tk) / (tk1 - tk);
                res = tout_v[k] + wgt * (tout_v[k + 1] - tout_v[k]);
            }
            r[st] = res;
        }
        tau[n] = make_float4(r[0], r[1], r[2], r[3]);
    }
}

// ---------------------------------------------------------------------------
// M2 = M@M (blocks 0..79: 4 rows x 320 cols, c = tid) fused with vec_kernel
// (block 80): vec's ~9us single-CU work hides under the matmul.
__global__ __launch_bounds__(320) void mm4r_vec_kernel(
    const float* __restrict__ A, float* __restrict__ C,
    const float* __restrict__ MT, const float* __restrict__ b0c,
    float* __restrict__ uv, const float* __restrict__ iv,
    float* __restrict__ W, float* __restrict__ out)
{
    const int b = blockIdx.x;
    const int tid = threadIdx.x;
    if (b < 80) {
        const int c = tid;
        const int r0 = b * 4;
        const float* Ar = A + (size_t)r0 * NP;
        float a0 = 0.f, a1 = 0.f, a2 = 0.f, a3 = 0.f;
        #pragma unroll 8
        for (int k = 0; k < NP; ++k) {
            const float bb = A[(size_t)k * NP + c];
            a0 = fmaf(Ar[k], bb, a0);
            a1 = fmaf(Ar[NP + k], bb, a1);
            a2 = fmaf(Ar[2 * NP + k], bb, a2);
            a3 = fmaf(Ar[3 * NP + k], bb, a3);
        }
        C[(size_t)r0 * NP + c] = a0;
        C[(size_t)(r0 + 1) * NP + c] = a1;
        C[(size_t)(r0 + 2) * NP + c] = a2;
        C[(size_t)(r0 + 3) * NP + c] = a3;
        return;
    }
    // ---- vec body (block 80): forcing vectors via MT column-matvecs ----
    __shared__ float ysB[NP], ysC[NP];
    const float s = DTH / 8.0f;
    const float b0 = b0c[tid];
    const float cc = b0c[NP + tid];
    ysB[tid] = b0; ysC[tid] = cc;
    __syncthreads();

    float mb, mc, m2b, m2c, m3b, m3c;
    {
        float aB = 0.f, aC = 0.f;
        #pragma unroll 8
        for (int k = 0; k < NP; ++k) {
            const float a = MT[(size_t)k * NP + tid];
            aB = fmaf(a, ysB[k], aB);
            aC = fmaf(a, ysC[k], aC);
        }
        mb = aB; mc = aC;
    }
    __syncthreads(); ysB[tid] = mb; ysC[tid] = mc; __syncthreads();
    {
        float aB = 0.f, aC = 0.f;
        #pragma unroll 8
        for (int k = 0; k < NP; ++k) {
            const float a = MT[(size_t)k * NP + tid];
            aB = fmaf(a, ysB[k], aB);
            aC = fmaf(a, ysC[k], aC);
        }
        m2b = aB; m2c = aC;
    }
    __syncthreads(); ysB[tid] = m2b; ysC[tid] = m2c; __syncthreads();
    {
        float aB = 0.f, aC = 0.f;
        #pragma unroll 8
        for (int k = 0; k < NP; ++k) {
            const float a = MT[(size_t)k * NP + tid];
            aB = fmaf(a, ysB[k], aB);
            aC = fmaf(a, ysC[k], aC);
        }
        m3b = aB; m3c = aC;
    }

    const float u1 = s * (b0 + mb + (1.0f / 3.0f) * (m2b + m3b));
    const float u2 = s * (3.0f * b0 + 2.0f * mb + m2b);
    const float u3 = s * (3.0f * b0 + mb);
    const float u4 = s * b0;
    const float dd = s * (8.0f * cc + 4.0f * mc + (4.0f / 3.0f) * m2c + (1.0f / 3.0f) * m3c);

    uv[tid]          = u1;
    uv[NP + tid]     = u2;
    uv[2 * NP + tid] = u3;
    uv[3 * NP + tid] = u4;
    uv[4 * NP + tid] = dd;

    W[(size_t)(0 << 7) * NP + tid] = dd;
    W[(size_t)(1 << 7) * NP + tid] = u1;
    W[(size_t)(2 << 7) * NP + tid] = u2;
    W[(size_t)(3 << 7) * NP + tid] = u3;
    W[(size_t)(4 << 7) * NP + tid] = u4;

    if (tid < NN) out[tid] = iv[tid];
}

// P = M2 @ (M/6 + M2/24) + (I + M + M2/2); also PT0 = P^T.
__global__ void matmulP(const float* __restrict__ M2, const float* __restrict__ M,
                        float* __restrict__ P, float* __restrict__ PT0)
{
    const int c = blockIdx.x * 64 + threadIdx.x;
    const int r0 = blockIdx.y * 4;
    const float* Ar = M2 + (size_t)r0 * NP;
    float a0 = 0.f, a1 = 0.f, a2 = 0.f, a3 = 0.f;
    #pragma unroll 8
    for (int k = 0; k < NP; ++k) {
        const size_t o = (size_t)k * NP + c;
        const float b = (1.0f / 6.0f) * M[o] + (1.0f / 24.0f) * M2[o];
        a0 = fmaf(Ar[k], b, a0);
        a1 = fmaf(Ar[NP + k], b, a1);
        a2 = fmaf(Ar[2 * NP + k], b, a2);
        a3 = fmaf(Ar[3 * NP + k], b, a3);
    }
    float acc[4] = {a0, a1, a2, a3};
    float4 t;
    #pragma unroll
    for (int u = 0; u < 4; ++u) {
        const int r = r0 + u;
        const size_t idx = (size_t)r * NP + c;
        float v = acc[u] + M[idx] + 0.5f * M2[idx];
        if (r == c && r < NN) v += 1.0f;
        P[idx] = v;
        ((float*)&t)[u] = v;
    }
    *(float4*)(PT0 + (size_t)c * NP + r0) = t;
}

// ---------------------------------------------------------------------------
// Fat ladder kernel.  Squaring block b<320; rider blocks:
//   j < 7 : W doubling (W has 5 families x 128 steps, row (v<<7)+m)
//   j >= 7: pair-combine Sout[k] = P^(2^j) Sin[2k] + Sin[2k+1]
// Squaring path: 4 independent accumulators (the single-acc FMA chain was a
// 320x4 = 1280-cyc latency floor per block at 1.25 blocks/CU).
__global__ __launch_bounds__(320) void fat_kernel(
    const float* __restrict__ src, float* __restrict__ dst,
    float* __restrict__ PTall, int j, float* __restrict__ W,
    const float* __restrict__ Sin, float* __restrict__ Sout, int npairs)
{
    const int b = blockIdx.x;
    const int tid = threadIdx.x;
    if (b < 320) {
        const int w = tid >> 6, l = tid & 63;
        const int r = (b & 63) * 5 + w;
        const int c = (b >> 6) * 64 + l;
        const float* Ar = src + (size_t)r * NP;
        float c0 = 0.f, c1 = 0.f, c2 = 0.f, c3 = 0.f;
        #pragma unroll 4
        for (int k = 0; k < NP; k += 4) {
            c0 = fmaf(Ar[k],     src[(size_t)k * NP + c],       c0);
            c1 = fmaf(Ar[k + 1], src[(size_t)(k + 1) * NP + c], c1);
            c2 = fmaf(Ar[k + 2], src[(size_t)(k + 2) * NP + c], c2);
            c3 = fmaf(Ar[k + 3], src[(size_t)(k + 3) * NP + c], c3);
        }
        const float acc = (c0 + c1) + (c2 + c3);
        dst[(size_t)r * NP + c] = acc;
        PTall[(size_t)(j + 1) * NP * NP + (size_t)c * NP + r] = acc;
        return;
    }
    const float* PTj = PTall + (size_t)j * NP * NP;
    const int c0 = (b - 320) * 4;
    __shared__ float ys[4][NP];
    if (j < 7) {
        const int nc = 5 << j;
        #pragma unroll
        for (int u = 0; u < 4; ++u) {
            const int ci = c0 + u;
            float val = 0.0f;
            if (ci < nc) {
                const int v = ci >> j, mo = ci & ((1 << j) - 1);
                val = W[(size_t)((v << 7) + mo) * NP + tid];
            }
            ys[u][tid] = val;
        }
        __syncthreads();
        float a0 = 0.f, a1 = 0.f, a2 = 0.f, a3 = 0.f;
        #pragma unroll 8
        for (int k = 0; k < NP; ++k) {
            const float p = PTj[(size_t)k * NP + tid];
            a0 = fmaf(p, ys[0][k], a0);
            a1 = fmaf(p, ys[1][k], a1);
            a2 = fmaf(p, ys[2][k], a2);
            a3 = fmaf(p, ys[3][k], a3);
        }
        const float acc[4] = {a0, a1, a2, a3};
        #pragma unroll
        for (int u = 0; u < 4; ++u) {
            const int ci = c0 + u;
            if (ci < nc) {
                const int v = ci >> j, mo = ci & ((1 << j) - 1);
                W[(size_t)((v << 7) + (1 << j) + mo) * NP + tid] = acc[u];
            }
        }
    } else {
        #pragma unroll
        for (int u = 0; u < 4; ++u) {
            const int k = c0 + u;
            ys[u][tid] = (k < npairs) ? Sin[(size_t)(2 * k) * NP + tid] : 0.0f;
        }
        __syncthreads();
        float a0 = 0.f, a1 = 0.f, a2 = 0.f, a3 = 0.f;
        #pragma unroll 8
        for (int k = 0; k < NP; ++k) {
            const float p = PTj[(size_t)k * NP + tid];
            a0 = fmaf(p, ys[0][k], a0);
            a1 = fmaf(p, ys[1][k], a1);
            a2 = fmaf(p, ys[2][k], a2);
            a3 = fmaf(p, ys[3][k], a3);
        }
        const float acc[4] = {a0, a1, a2, a3};
        #pragma unroll
        for (int u = 0; u < 4; ++u) {
            const int k = c0 + u;
            if (k < npairs)
                Sout[(size_t)k * NP + tid] = acc[u] + Sin[(size_t)(2 * k + 1) * NP + tid];
        }
    }
}

// ---------------------------------------------------------------------------
// G_c for 4 consecutive c per block (W loads reused 4x -> L2 traffic /4).
// grid (5, 120) x 64; pad c>=468 -> 0 (tau index clamped in-bounds).
__global__ void gsum_kernel(const float* __restrict__ W,
                            const float4* __restrict__ tau,
                            float* __restrict__ G)
{
    const int r = blockIdx.x * 64 + threadIdx.x;
    const int c0 = blockIdx.y * 4;
    const float* W0 = W;
    const float* W1 = W + 1 * (size_t)L_CHUNK * NP;
    const float* W2 = W + 2 * (size_t)L_CHUNK * NP;
    const float* W3 = W + 3 * (size_t)L_CHUNK * NP;
    const float* W4 = W + 4 * (size_t)L_CHUNK * NP;
    const int cc0 = (c0     < N_BND) ? c0     : N_BND - 1;
    const int cc1 = (c0 + 1 < N_BND) ? c0 + 1 : N_BND - 1;
    const int cc2 = (c0 + 2 < N_BND) ? c0 + 2 : N_BND - 1;
    const int cc3 = (c0 + 3 < N_BND) ? c0 + 3 : N_BND - 1;
    const int nb0 = cc0 * L_CHUNK + L_CHUNK - 1;
    const int nb1 = cc1 * L_CHUNK + L_CHUNK - 1;
    const int nb2 = cc2 * L_CHUNK + L_CHUNK - 1;
    const int nb3 = cc3 * L_CHUNK + L_CHUNK - 1;
    float g0 = 0.f, g1 = 0.f, g2 = 0.f, g3 = 0.f;
    #pragma unroll 2
    for (int m = 0; m < L_CHUNK; ++m) {
        const float4 a0 = tau[nb0 - m];
        const float4 a1 = tau[nb1 - m];
        const float4 a2 = tau[nb2 - m];
        const float4 a3 = tau[nb3 - m];
        const size_t o = (size_t)m * NP + r;
        const float w0 = W0[o], w1 = W1[o], w2 = W2[o], w3 = W3[o], w4 = W4[o];
        float t;
        t = w0; t = fmaf(a0.x, w1, t); t = fmaf(a0.y, w2, t);
        t = fmaf(a0.z, w3, t); t = fmaf(a0.w, w4, t); g0 += t;
        t = w0; t = fmaf(a1.x, w1, t); t = fmaf(a1.y, w2, t);
        t = fmaf(a1.z, w3, t); t = fmaf(a1.w, w4, t); g1 += t;
        t = w0; t = fmaf(a2.x, w1, t); t = fmaf(a2.y, w2, t);
        t = fmaf(a2.z, w3, t); t = fmaf(a2.w, w4, t); g2 += t;
        t = w0; t = fmaf(a3.x, w1, t); t = fmaf(a3.y, w2, t);
        t = fmaf(a3.z, w3, t); t = fmaf(a3.w, w4, t); g3 += t;
    }
    G[(size_t)(c0    ) * NP + r] = (c0     < N_BND) ? g0 : 0.f;
    G[(size_t)(c0 + 1) * NP + r] = (c0 + 1 < N_BND) ? g1 : 0.f;
    G[(size_t)(c0 + 2) * NP + r] = (c0 + 2 < N_BND) ? g2 : 0.f;
    G[(size_t)(c0 + 3) * NP + r] = (c0 + 3 < N_BND) ? g3 : 0.f;
}

// ---------------------------------------------------------------------------
// Engine helpers.
// Lane l's accumulators cover rows {4l+k, k<4} and {256+l} of the wave's
// 40-column strip [40w, 40w+40) (row remap so partial writes vectorize).
__device__ __forceinline__ void load_pfrag(const float* __restrict__ Psrc,
                                           vf2 p[5][20], int l, int w)
{
    #pragma unroll
    for (int k = 0; k < 5; ++k) {
        const int row = (k < 4) ? (4 * l + k) : (256 + l);
        const float* Pr = Psrc + (size_t)row * NP + 40 * w;
        #pragma unroll
        for (int j4 = 0; j4 < 10; ++j4) {
            const float4 v4 = *(const float4*)(Pr + 4 * j4);
            vf2 a; a.x = v4.x; a.y = v4.y;
            vf2 b; b.x = v4.z; b.y = v4.w;
            p[k][2 * j4] = a;
            p[k][2 * j4 + 1] = b;
        }
    }
    #pragma unroll
    for (int k = 0; k < 5; ++k)
        #pragma unroll
        for (int jj = 0; jj < 20; jj += 4)
            PIN4(p[k][jj], p[k][jj + 1], p[k][jj + 2], p[k][jj + 3]);
}

// FMA phase: partial dots of this wave's rows over cols [40w,40w+40), y read
// from LDS broadcast; partials written b128 (rows 4l..4l+3) + b32 (256+l).
__device__ __forceinline__ void fma_phase(const vf2 p[5][20],
                                          const float* __restrict__ yb,
                                          float* __restrict__ pw, int l)
{
    vf2 a0 = {0.f, 0.f}, a1 = {0.f, 0.f}, a2 = {0.f, 0.f},
        a3 = {0.f, 0.f}, a4 = {0.f, 0.f};
    #pragma unroll
    for (int j4 = 0; j4 < 10; ++j4) {
        const float4 yv = *(const float4*)(yb + 4 * j4);
        vf2 y01; y01.x = yv.x; y01.y = yv.y;
        vf2 y23; y23.x = yv.z; y23.y = yv.w;
        const int jj = 2 * j4;
        PKFMA(a0, p[0][jj], y01); PKFMA(a0, p[0][jj + 1], y23);
        PKFMA(a1, p[1][jj], y01); PKFMA(a1, p[1][jj + 1], y23);
        PKFMA(a2, p[2][jj], y01); PKFMA(a2, p[2][jj + 1], y23);
        PKFMA(a3, p[3][jj], y01); PKFMA(a3, p[3][jj + 1], y23);
        PKFMA(a4, p[4][jj], y01); PKFMA(a4, p[4][jj + 1], y23);
    }
    float4 h4;
    h4.x = a0.x + a0.y;
    h4.y = a1.x + a1.y;
    h4.z = a2.x + a2.y;
    h4.w = a3.x + a3.y;
    *(float4*)(pw + 4 * l) = h4;          // rows 4l..4l+3 (16B aligned)
    pw[256 + l] = a4.x + a4.y;            // row 256+l
}

// Reduce row r: sum the 8 waves' partials (partials stored at [wave][row]).
__device__ __forceinline__ float reduce8(const float* __restrict__ pb, int r)
{
    float s = pb[r];
    #pragma unroll
    for (int k = 1; k < 8; ++k) s += pb[k * NP + r];
    return s;
}

// ---------------------------------------------------------------------------
// Level-2 boundary: Z_{g+1} = P^2048 Z_g + S4_g.  1 WG x 512, 29 steps.
__global__ ENGINE_LO void bscan_kernel(
    const float* __restrict__ PK, const float* __restrict__ S4,
    const float* __restrict__ iv, float* __restrict__ Z)
{
    const int tid = threadIdx.x;
    const int w = tid >> 6, l = tid & 63;
    vf2 p[5][20];
    load_pfrag(PK, p, l, w);

    __shared__ float ybuf[NP];
    __shared__ float part[2 * 8 * NP];
    __shared__ float ring[NSCAN * NP];

    const int r = 40 * w + l;   // valid when l < 40
    if (tid < NP) {
        const float y0 = (tid < NN) ? iv[tid] : 0.f;
        ybuf[tid] = y0;
        Z[tid] = y0;
    }
    float sv = (l < 40) ? S4[r] : 0.f;
    __syncthreads();

    for (int g = 0; g < NSCAN; ++g) {
        float* pb = part + (g & 1) * 8 * NP;
        fma_phase(p, ybuf + 40 * w, pb + w * NP, l);
        const float svn = (l < 40 && g + 1 < NSCAN)
                        ? S4[(size_t)(g + 1) * NP + r] : 0.f;
        __syncthreads();
        if (l < 40) {
            const float yn = reduce8(pb, r) + sv;
            ybuf[r] = yn;
            ring[g * NP + r] = yn;
        }
        sv = svn;
    }
    __syncthreads();
    for (int s2 = 0; s2 < NSCAN; ++s2)
        for (int j = tid; j < NP; j += 512)
            Z[(size_t)(s2 + 1) * NP + j] = ring[s2 * NP + j];
}

// ---------------------------------------------------------------------------
// Level-2 refill: Y_{16g+i+1} = P^128 Y_{16g+i} + G_{16g+i}.  30 WGs x 512.
__global__ ENGINE_LO void brefill_kernel(
    const float* __restrict__ PL, const float* __restrict__ G,
    const float* __restrict__ Z, float* __restrict__ Y)
{
    const int tid = threadIdx.x;
    const int w = tid >> 6, l = tid & 63;
    vf2 p[5][20];
    load_pfrag(PL, p, l, w);

    __shared__ float ybuf[NP];
    __shared__ float part[2 * 8 * NP];
    __shared__ float ring[16 * NP];

    const int g = blockIdx.x;
    const int nsteps = (16 * g + 16 <= N_BND) ? 16 : (N_BND - 16 * g);
    const int r = 40 * w + l;
    if (tid < NP) {
        const float z = Z[(size_t)g * NP + tid];
        ybuf[tid] = z;
        if (g == 0) Y[tid] = z;
    }
    float gv = (l < 40) ? G[(size_t)(16 * g) * NP + r] : 0.f;
    __syncthreads();

    for (int i = 0; i < nsteps; ++i) {
        float* pb = part + (i & 1) * 8 * NP;
        fma_phase(p, ybuf + 40 * w, pb + w * NP, l);
        const float gvn = (l < 40 && i + 1 < nsteps)
                        ? G[(size_t)(16 * g + i + 1) * NP + r] : 0.f;
        __syncthreads();
        if (l < 40) {
            const float yn = reduce8(pb, r) + gv;
            ybuf[r] = yn;
            ring[i * NP + r] = yn;
        }
        gv = gvn;
    }
    __syncthreads();
    for (int s2 = 0; s2 < nsteps; ++s2)
        for (int j = tid; j < NP; j += 512)
            Y[(size_t)(16 * g + 1 + s2) * NP + j] = ring[s2 * NP + j];
}

// ---------------------------------------------------------------------------
// Level-1 refill (r11/r14 structure, proven ~274us): 235 WGs x 512; WG b
// advances TWO chains (chunks 2b and 2b+1) half a step apart, sharing one
// register-resident P:
//   phase1: fmaA(i) + reduceB(i-1)  -> barrier
//   phase2: fmaB(i) + reduceA(i)    -> barrier
__global__ ENGINE_LO void refill_kernel(
    const float* __restrict__ P, const float* __restrict__ uv,
    const float4* __restrict__ tau, const float* __restrict__ Y,
    float* __restrict__ out)
{
    const int tid = threadIdx.x;
    const int w = tid >> 6, l = tid & 63;
    vf2 p[5][20];
    load_pfrag(P, p, l, w);

    __shared__ float ybufA[NP], ybufB[NP];
    __shared__ float partA[8 * NP], partB[8 * NP];
    __shared__ float ringA[8 * NP], ringB[8 * NP];
    __shared__ float4 tausA[8], tausB[8];

    const int r = 40 * w + l;
    float du0 = 0.f, du1 = 0.f, du2 = 0.f, du3 = 0.f, dd = 0.f;
    if (l < 40) {
        du0 = uv[r]; du1 = uv[NP + r]; du2 = uv[2 * NP + r];
        du3 = uv[3 * NP + r]; dd = uv[4 * NP + r];
    }

    const int b = blockIdx.x;
    const int cA = 2 * b, cB = 2 * b + 1;
    const int n0A = cA * L_CHUNK;
    const int n0B = cB * L_CHUNK;
    const int nA = (n0A + L_CHUNK < TS) ? L_CHUNK : (TS - n0A);
    const bool hasB = (cB < N_CHUNK);   // when true, nB == nA == 128

    if (tid < NP) {
        ybufA[tid] = Y[(size_t)cA * NP + tid];
        if (hasB) ybufB[tid] = Y[(size_t)cB * NP + tid];
    }
    if (tid < 8) {
        if (tid < nA) tausA[tid] = tau[n0A + tid];
        if (hasB) tausB[tid] = tau[n0B + tid];
    }
    int wsA = 0, wsB = 0;
    __syncthreads();

    for (int i = 0; i < nA; ++i) {
        // ---------------- phase 1: flushA? ; fmaA(i) ; reduceB(i-1)
        if (i - wsA == 8) {
            #pragma unroll 1
            for (int s2 = 0; s2 < 8; ++s2) {
                const size_t row = (size_t)(n0A + wsA + 1 + s2);
                for (int j = tid; j < NN; j += 512)
                    out[row * NN + j] = ringA[s2 * NP + j];
            }
            wsA = i;
            if (tid < 8 && i + tid < nA) tausA[tid] = tau[n0A + i + tid];
        }
        fma_phase(p, ybufA + 40 * w, partA + w * NP, l);
        if (hasB && i > 0) {
            const int sb = (i - 1) - wsB;
            const float4 a = tausB[sb];
            if (l < 40) {
                float yn = reduce8(partB, r) + dd;
                yn = fmaf(a.x, du0, yn);
                yn = fmaf(a.y, du1, yn);
                yn = fmaf(a.z, du2, yn);
                yn = fmaf(a.w, du3, yn);
                ybufB[r] = yn;
                ringB[sb * NP + r] = yn;
            }
        }
        __syncthreads();
        // ---------------- phase 2: flushB? ; fmaB(i) ; reduceA(i)
        if (hasB && i - wsB == 8) {
            #pragma unroll 1
            for (int s2 = 0; s2 < 8; ++s2) {
                const size_t row = (size_t)(n0B + wsB + 1 + s2);
                for (int j = tid; j < NN; j += 512)
                    out[row * NN + j] = ringB[s2 * NP + j];
            }
            wsB = i;
            if (tid < 8) tausB[tid] = tau[n0B + i + tid];
        }
        if (hasB) fma_phase(p, ybufB + 40 * w, partB + w * NP, l);
        {
            const int sa = i - wsA;
            const float4 a = tausA[sa];
            if (l < 40) {
                float yn = reduce8(partA, r) + dd;
                yn = fmaf(a.x, du0, yn);
                yn = fmaf(a.y, du1, yn);
                yn = fmaf(a.z, du2, yn);
                yn = fmaf(a.w, du3, yn);
                ybufA[r] = yn;
                ringA[sa * NP + r] = yn;
            }
        }
        __syncthreads();
    }

    // post-loop: reduceB(nA-1), then tail flushes
    if (hasB) {
        const int sb = (nA - 1) - wsB;
        const float4 a = tausB[sb];
        if (l < 40) {
            float yn = reduce8(partB, r) + dd;
            yn = fmaf(a.x, du0, yn);
            yn = fmaf(a.y, du1, yn);
            yn = fmaf(a.z, du2, yn);
            yn = fmaf(a.w, du3, yn);
            ringB[sb * NP + r] = yn;
        }
    }
    __syncthreads();
    {
        const int cntA = nA - wsA;
        for (int s2 = 0; s2 < cntA; ++s2) {
            const size_t row = (size_t)(n0A + wsA + 1 + s2);
            for (int j = tid; j < NN; j += 512)
                out[row * NN + j] = ringA[s2 * NP + j];
        }
        if (hasB) {
            const int cntB = nA - wsB;
            for (int s2 = 0; s2 < cntB; ++s2) {
                const size_t row = (size_t)(n0B + wsB + 1 + s2);
                for (int j = tid; j < NN; j += 512)
                    out[row * NN + j] = ringB[s2 * NP + j];
            }
        }
    }
}

// ---------------------------------------------------------------------------
extern "C" void kernel_launch(void* const* d_in, const int* in_sizes, int n_in,
                              void* d_out, int out_size, void* d_ws, size_t ws_size,
                              hipStream_t stream)
{
    const float* params = (const float*)d_in[0];
    const float* tlo    = (const float*)d_in[1];
    const float* thi    = (const float*)d_in[2];
    const float* B      = (const float*)d_in[3];
    const float* tout_t = (const float*)d_in[4];
    const float* tout_v = (const float*)d_in[5];
    const float* iv     = (const float*)d_in[6];
    const int*   t0     = (const int*)d_in[8];
    float* out = (float*)d_out;
    float* ws  = (float*)d_ws;

    float*  M    = ws + WS_M;
    float*  MT   = ws + WS_MT;
    float*  M2   = ws + WS_M2;
    float*  P    = ws + WS_P;
    float*  UV   = ws + WS_UV;
    float*  B0C  = ws + WS_B0C;
    float4* TAU  = (float4*)(ws + WS_TAU);
    float*  W    = ws + WS_W;
    float*  G    = ws + WS_G;
    float*  Y    = ws + WS_Y;
    float*  Z    = ws + WS_Z;
    float*  SA   = ws + WS_SA;
    float*  SB   = ws + WS_SB;
    float*  PL   = ws + WS_PL;
    float*  PA   = ws + WS_PA;
    float*  PB   = ws + WS_PB;
    float*  PT   = ws + WS_PT;     // slot j: transpose of P^(2^j)

    // Phase A (fused): buildrow + b0c + tau in one launch
    phaseA_kernel<<<619, 320, 0, stream>>>(params, tlo, thi, B, tout_t,
                                           tout_v, t0, M, MT, B0C, TAU);

    // M2 = M@M fused with vec (forcing vectors, W seed, out row 0)
    mm4r_vec_kernel<<<81, 320, 0, stream>>>(M, M2, MT, B0C, UV, iv, W, out);

    // P = M2@(M/6+M2/24) + I + M + M2/2 (+ PT[0])
    matmulP<<<dim3(5, 80), 64, 0, stream>>>(M2, M, P, PT);

    // Squaring ladder with riders.
    // j=0..6: W doubling riders; dst of j=6 is PL = P^128.
    const float* src = P;
    for (int j = 0; j < 7; ++j) {
        float* dst = (j == 6) ? PL : ((j & 1) ? PB : PA);
        const int aux = ((5 << j) + 3) / 4;
        fat_kernel<<<320 + aux, 320, 0, stream>>>(src, dst, PT, j, W,
                                                  nullptr, nullptr, 0);
        src = dst;
    }
    // Boundary forcing sums over each 128-step chunk (4 c's per block).
    gsum_kernel<<<dim3(5, NB_PAD / 4), 64, 0, stream>>>(W, TAU, G);
    // j=7..10: pair-combine riders 480 -> 240 -> 120 -> 60 -> 30 group sums.
    const float* Spp[5] = { G, SA, SB, SA, SB };
    for (int j = 7; j < 11; ++j) {
        float* dst = (j & 1) ? PB : PA;
        const int npairs = 30720 >> j;     // 240, 120, 60, 30
        const int aux = (npairs + 3) / 4;
        fat_kernel<<<320 + aux, 320, 0, stream>>>(src, dst, PT, j, W,
                                                  Spp[j - 7], (float*)Spp[j - 6], npairs);
        src = dst;
    }
    // src == PA == P^2048; SB holds 30 group sums

    // Level-2 boundary chain + level-2 refill of Y
    bscan_kernel<<<1, 512, 0, stream>>>(PA, SB, iv, Z);
    brefill_kernel<<<N_GRP, 512, 0, stream>>>(PL, G, Z, Y);

    // Level-1 parallel refill (2 chains per WG)
    refill_kernel<<<N_WG2, 512, 0, stream>>>(P, UV, TAU, Y, out);
}

// Round 11
// 669.264 us; speedup vs baseline: 1.4309x; 1.0288x over previous
//
#include <hip/hip_runtime.h>
#include <math.h>

// Problem constants
#define NN     302      // state dim (N_ROOMS + 2)
#define MM     301      // input dim (N_ROOMS + 1)
#define NROOMS 300
#define NP     320      // padded dim
#define TS     59999    // number of steps
#define KN     2001     // tout knots
#define DTH    30.0f

// Time-chunking (L_CHUNK=128; two chains per WG share one register-resident
// P copy — r10/r15: any config that shrinks the per-wave register budget
// below P's footprint forces L2 remat of P every step and is 2-11x slower.
// 8-wave ENGINE_LO is the proven config: ~274us refill.)
// r18 = r17 + fat squaring reshaped to mm4r's proven 4-rows-per-thread
// blocking (r16 lesson: reuse > block-count for L2-resident 320^3 panels;
// fat was the one matmul still at 1-output/thread).
#define L_CHUNK 128     // steps per chunk (level 1)
#define N_CHUNK 469     // ceil(59999/128) chunks
#define N_WG2   235     // refill WGs (2 chains each)
#define N_BND   468     // boundary steps
#define NB_PAD  480     // padded boundary count (30 groups of 16)
#define N_GRP   30      // level-2 groups
#define NSCAN   29      // level-2 boundary-chain steps

// Workspace layout (in floats)
#define WS_M    0        // 102400
#define WS_M2   102400   // 102400
#define WS_P    204800   // 102400
#define WS_UV   307200   // 1600
#define WS_B0C  308800   // 640
#define WS_TAU  309440   // 240000 (float4 x 59999)
#define WS_W    549440   // 5 x 128 x 320 = 204800
#define WS_G    754240   // 480 x 320 = 153600
#define WS_Y    907840   // 469 x 320 = 150080
#define WS_Z    1057920  // 30 x 320 = 9600
#define WS_SA   1067520  // 240 x 320 = 76800
#define WS_SB   1144320  // 120 x 320 = 38400
#define WS_PL   1182720  // 102400  P^128 row-major
#define WS_PA   1285120  // 102400  ladder ping
#define WS_PB   1387520  // 102400  ladder pong
#define WS_PT   1489920  // 12 x 102400 (transposed powers, slot j = (P^(2^j))^T)
#define WS_MT   2718720  // 102400  M^T
                         // total 2821120 floats = 11.28 MB

typedef float vf2 __attribute__((ext_vector_type(2)));

// 512-thread engine: 8 waves; wave w owns cols [40w,40w+40) of P; lane l's
// accumulators cover rows {4l+k, k<4} and {256+l} (partial writes are
// 1 x ds_write_b128 + 1 x b32).  y broadcast via LDS ybuf.
#define ENGINE_LO __launch_bounds__(512) __attribute__((amdgpu_waves_per_eu(2, 2)))
#define PKFMA(acc, a, b) asm("v_pk_fma_f32 %0, %1, %2, %0" : "+v"(acc) : "v"(a), "v"(b))
#define PIN4(a, b, c, d) asm volatile("" : "+v"(a), "+v"(b), "+v"(c), "+v"(d))

// ---------------------------------------------------------------------------
// Phase-A mega-kernel: blocks 0..319 buildrow; 320..383 b0c (5 rows/block);
// 384..618 tau.  All independent — one launch, whole-GPU utilization.
__global__ __launch_bounds__(320) void phaseA_kernel(
    const float* __restrict__ params, const float* __restrict__ tlo,
    const float* __restrict__ thi, const float* __restrict__ B,
    const float* __restrict__ tout_t, const float* __restrict__ tout_v,
    const int* __restrict__ t0p,
    float* __restrict__ M, float* __restrict__ MT,
    float* __restrict__ b0c, float4* __restrict__ tau)
{
    __shared__ float red[5];
    __shared__ float Qs[NROOMS];
    const int b = blockIdx.x;
    const int tid = threadIdx.x;

    if (b < 320) {
        // ---- buildrow: M = DTH*W with diag -= DTH*sum|W[r,:]| ----
        const int r = b;
        const int c = tid;
        float wv = 0.0f;
        if (r < NN && c < NN) {
            const int idx = r * NN + c;
            const float x = 1.0f / (1.0f + expf(-params[idx]));
            wv = tlo[idx] + (thi[idx] - tlo[idx]) * x;
        }
        float s = fabsf(wv);
        #pragma unroll
        for (int off = 32; off > 0; off >>= 1) s += __shfl_xor(s, off, 64);
        if ((c & 63) == 0) red[c >> 6] = s;
        __syncthreads();
        const float rs = red[0] + red[1] + red[2] + red[3] + red[4];
        float v = DTH * wv;
        if (r == c) v -= DTH * rs;
        M[r * NP + c] = v;
        MT[(size_t)c * NP + r] = v;
    } else if (b < 384) {
        // ---- b0c: wave w of this block handles row r = (b-320)*5 + w ----
        for (int q = tid; q < NROOMS; q += 320) {
            const int idx = NN * NN + q;
            const float x = 1.0f / (1.0f + expf(-params[idx]));
            Qs[q] = tlo[idx] + (thi[idx] - tlo[idx]) * x;
        }
        __syncthreads();
        const int w = tid >> 6, l = tid & 63;
        const int r = (b - 320) * 5 + w;
        if (r >= NN) {
            if (l == 0) { b0c[r] = 0.0f; b0c[NP + r] = 0.0f; }
            return;
        }
        float s = 0.0f;
        for (int q = l; q < NROOMS; q += 64) s = fmaf(B[r * MM + 1 + q], Qs[q], s);
        #pragma unroll
        for (int off = 32; off > 0; off >>= 1) s += __shfl_xor(s, off, 64);
        if (l == 0) { b0c[r] = B[r * MM]; b0c[NP + r] = s; }
    } else {
        // ---- tau: per-step Tout interp coefficients (np.interp clone) ----
        if (tid >= 256) return;
        const int n = (b - 384) * 256 + tid;
        if (n >= TS) return;
        const float tbase = 30.0f * (float)n + (float)(*t0p);
        float r[4];
        #pragma unroll
        for (int st = 0; st < 4; ++st) {
            const float x = tbase + 10.0f * (float)st;
            float res;
            if (x <= tout_t[0])            res = tout_v[0];
            else if (x >= tout_t[KN - 1])  res = tout_v[KN - 1];
            else {
                int k = (int)(x * (1.0f / 900.0f));
                if (k > KN - 2) k = KN - 2;
                if (k < 0) k = 0;
                if (x < tout_t[k] && k > 0) --k;
                else if (x >= tout_t[k + 1] && k < KN - 2) ++k;
                const float tk = tout_t[k], tk1 = tout_t[k + 1];
                const float wgt = (x - tk) / (tk1 - tk);
                res = tout_v[k] + wgt * (tout_v[k + 1] - tout_v[k]);
            }
            r[st] = res;
        }
        tau[n] = make_float4(r[0], r[1], r[2], r[3]);
    }
}

// ---------------------------------------------------------------------------
// M2 = M@M (blocks 0..79: 4 rows x 320 cols, c = tid) fused with vec_kernel
// (block 80): vec's ~9us single-CU work hides under the matmul.
__global__ __launch_bounds__(320) void mm4r_vec_kernel(
    const float* __restrict__ A, float* __restrict__ C,
    const float* __restrict__ MT, const float* __restrict__ b0c,
    float* __restrict__ uv, const float* __restrict__ iv,
    float* __restrict__ W, float* __restrict__ out)
{
    const int b = blockIdx.x;
    const int tid = threadIdx.x;
    if (b < 80) {
        const int c = tid;
        const int r0 = b * 4;
        const float* Ar = A + (size_t)r0 * NP;
        float a0 = 0.f, a1 = 0.f, a2 = 0.f, a3 = 0.f;
        #pragma unroll 8
        for (int k = 0; k < NP; ++k) {
            const float bb = A[(size_t)k * NP + c];
            a0 = fmaf(Ar[k], bb, a0);
            a1 = fmaf(Ar[NP + k], bb, a1);
            a2 = fmaf(Ar[2 * NP + k], bb, a2);
            a3 = fmaf(Ar[3 * NP + k], bb, a3);
        }
        C[(size_t)r0 * NP + c] = a0;
        C[(size_t)(r0 + 1) * NP + c] = a1;
        C[(size_t)(r0 + 2) * NP + c] = a2;
        C[(size_t)(r0 + 3) * NP + c] = a3;
        return;
    }
    // ---- vec body (block 80): forcing vectors via MT column-matvecs ----
    __shared__ float ysB[NP], ysC[NP];
    const float s = DTH / 8.0f;
    const float b0 = b0c[tid];
    const float cc = b0c[NP + tid];
    ysB[tid] = b0; ysC[tid] = cc;
    __syncthreads();

    float mb, mc, m2b, m2c, m3b, m3c;
    {
        float aB = 0.f, aC = 0.f;
        #pragma unroll 8
        for (int k = 0; k < NP; ++k) {
            const float a = MT[(size_t)k * NP + tid];
            aB = fmaf(a, ysB[k], aB);
            aC = fmaf(a, ysC[k], aC);
        }
        mb = aB; mc = aC;
    }
    __syncthreads(); ysB[tid] = mb; ysC[tid] = mc; __syncthreads();
    {
        float aB = 0.f, aC = 0.f;
        #pragma unroll 8
        for (int k = 0; k < NP; ++k) {
            const float a = MT[(size_t)k * NP + tid];
            aB = fmaf(a, ysB[k], aB);
            aC = fmaf(a, ysC[k], aC);
        }
        m2b = aB; m2c = aC;
    }
    __syncthreads(); ysB[tid] = m2b; ysC[tid] = m2c; __syncthreads();
    {
        float aB = 0.f, aC = 0.f;
        #pragma unroll 8
        for (int k = 0; k < NP; ++k) {
            const float a = MT[(size_t)k * NP + tid];
            aB = fmaf(a, ysB[k], aB);
            aC = fmaf(a, ysC[k], aC);
        }
        m3b = aB; m3c = aC;
    }

    const float u1 = s * (b0 + mb + (1.0f / 3.0f) * (m2b + m3b));
    const float u2 = s * (3.0f * b0 + 2.0f * mb + m2b);
    const float u3 = s * (3.0f * b0 + mb);
    const float u4 = s * b0;
    const float dd = s * (8.0f * cc + 4.0f * mc + (4.0f / 3.0f) * m2c + (1.0f / 3.0f) * m3c);

    uv[tid]          = u1;
    uv[NP + tid]     = u2;
    uv[2 * NP + tid] = u3;
    uv[3 * NP + tid] = u4;
    uv[4 * NP + tid] = dd;

    W[(size_t)(0 << 7) * NP + tid] = dd;
    W[(size_t)(1 << 7) * NP + tid] = u1;
    W[(size_t)(2 << 7) * NP + tid] = u2;
    W[(size_t)(3 << 7) * NP + tid] = u3;
    W[(size_t)(4 << 7) * NP + tid] = u4;

    if (tid < NN) out[tid] = iv[tid];
}

// P = M2 @ (M/6 + M2/24) + (I + M + M2/2); also PT0 = P^T.
__global__ void matmulP(const float* __restrict__ M2, const float* __restrict__ M,
                        float* __restrict__ P, float* __restrict__ PT0)
{
    const int c = blockIdx.x * 64 + threadIdx.x;
    const int r0 = blockIdx.y * 4;
    const float* Ar = M2 + (size_t)r0 * NP;
    float a0 = 0.f, a1 = 0.f, a2 = 0.f, a3 = 0.f;
    #pragma unroll 8
    for (int k = 0; k < NP; ++k) {
        const size_t o = (size_t)k * NP + c;
        const float b = (1.0f / 6.0f) * M[o] + (1.0f / 24.0f) * M2[o];
        a0 = fmaf(Ar[k], b, a0);
        a1 = fmaf(Ar[NP + k], b, a1);
        a2 = fmaf(Ar[2 * NP + k], b, a2);
        a3 = fmaf(Ar[3 * NP + k], b, a3);
    }
    float acc[4] = {a0, a1, a2, a3};
    float4 t;
    #pragma unroll
    for (int u = 0; u < 4; ++u) {
        const int r = r0 + u;
        const size_t idx = (size_t)r * NP + c;
        float v = acc[u] + M[idx] + 0.5f * M2[idx];
        if (r == c && r < NN) v += 1.0f;
        P[idx] = v;
        ((float*)&t)[u] = v;
    }
    *(float4*)(PT0 + (size_t)c * NP + r0) = t;
}

// ---------------------------------------------------------------------------
// Fat ladder kernel.  r18 squaring (b<80): mm4r's proven 4-rows-per-thread
// blocking — thread (b,tid) computes rows 4b..4b+3 x col tid; B-column load
// reused across 4 independent FMA chains; PT write is one float4 transpose
// store (matmulP's pattern; 4b is 16B-aligned).  Riders: b>=80, unchanged.
//   j < 7 : W doubling (W has 5 families x 128 steps, row (v<<7)+m)
//   j >= 7: pair-combine Sout[k] = P^(2^j) Sin[2k] + Sin[2k+1]
__global__ __launch_bounds__(320) void fat_kernel(
    const float* __restrict__ src, float* __restrict__ dst,
    float* __restrict__ PTall, int j, float* __restrict__ W,
    const float* __restrict__ Sin, float* __restrict__ Sout, int npairs)
{
    const int b = blockIdx.x;
    const int tid = threadIdx.x;
    if (b < 80) {
        const int c = tid;
        const int r0 = b * 4;
        const float* Ar = src + (size_t)r0 * NP;
        float a0 = 0.f, a1 = 0.f, a2 = 0.f, a3 = 0.f;
        #pragma unroll 8
        for (int k = 0; k < NP; ++k) {
            const float bb = src[(size_t)k * NP + c];
            a0 = fmaf(Ar[k], bb, a0);
            a1 = fmaf(Ar[NP + k], bb, a1);
            a2 = fmaf(Ar[2 * NP + k], bb, a2);
            a3 = fmaf(Ar[3 * NP + k], bb, a3);
        }
        dst[(size_t)(r0    ) * NP + c] = a0;
        dst[(size_t)(r0 + 1) * NP + c] = a1;
        dst[(size_t)(r0 + 2) * NP + c] = a2;
        dst[(size_t)(r0 + 3) * NP + c] = a3;
        float4 t;
        t.x = a0; t.y = a1; t.z = a2; t.w = a3;
        *(float4*)(PTall + (size_t)(j + 1) * NP * NP + (size_t)c * NP + r0) = t;
        return;
    }
    const float* PTj = PTall + (size_t)j * NP * NP;
    const int c0 = (b - 80) * 4;
    __shared__ float ys[4][NP];
    if (j < 7) {
        const int nc = 5 << j;
        #pragma unroll
        for (int u = 0; u < 4; ++u) {
            const int ci = c0 + u;
            float val = 0.0f;
            if (ci < nc) {
                const int v = ci >> j, mo = ci & ((1 << j) - 1);
                val = W[(size_t)((v << 7) + mo) * NP + tid];
            }
            ys[u][tid] = val;
        }
        __syncthreads();
        float a0 = 0.f, a1 = 0.f, a2 = 0.f, a3 = 0.f;
        #pragma unroll 8
        for (int k = 0; k < NP; ++k) {
            const float p = PTj[(size_t)k * NP + tid];
            a0 = fmaf(p, ys[0][k], a0);
            a1 = fmaf(p, ys[1][k], a1);
            a2 = fmaf(p, ys[2][k], a2);
            a3 = fmaf(p, ys[3][k], a3);
        }
        const float acc[4] = {a0, a1, a2, a3};
        #pragma unroll
        for (int u = 0; u < 4; ++u) {
            const int ci = c0 + u;
            if (ci < nc) {
                const int v = ci >> j, mo = ci & ((1 << j) - 1);
                W[(size_t)((v << 7) + (1 << j) + mo) * NP + tid] = acc[u];
            }
        }
    } else {
        #pragma unroll
        for (int u = 0; u < 4; ++u) {
            const int k = c0 + u;
            ys[u][tid] = (k < npairs) ? Sin[(size_t)(2 * k) * NP + tid] : 0.0f;
        }
        __syncthreads();
        float a0 = 0.f, a1 = 0.f, a2 = 0.f, a3 = 0.f;
        #pragma unroll 8
        for (int k = 0; k < NP; ++k) {
            const float p = PTj[(size_t)k * NP + tid];
            a0 = fmaf(p, ys[0][k], a0);
            a1 = fmaf(p, ys[1][k], a1);
            a2 = fmaf(p, ys[2][k], a2);
            a3 = fmaf(p, ys[3][k], a3);
        }
        const float acc[4] = {a0, a1, a2, a3};
        #pragma unroll
        for (int u = 0; u < 4; ++u) {
            const int k = c0 + u;
            if (k < npairs)
                Sout[(size_t)k * NP + tid] = acc[u] + Sin[(size_t)(2 * k + 1) * NP + tid];
        }
    }
}

// ---------------------------------------------------------------------------
// G_c for 4 consecutive c per block (W loads reused 4x -> L2 traffic /4).
// grid (5, 120) x 64; pad c>=468 -> 0 (tau index clamped in-bounds).
__global__ void gsum_kernel(const float* __restrict__ W,
                            const float4* __restrict__ tau,
                            float* __restrict__ G)
{
    const int r = blockIdx.x * 64 + threadIdx.x;
    const int c0 = blockIdx.y * 4;
    const float* W0 = W;
    const float* W1 = W + 1 * (size_t)L_CHUNK * NP;
    const float* W2 = W + 2 * (size_t)L_CHUNK * NP;
    const float* W3 = W + 3 * (size_t)L_CHUNK * NP;
    const float* W4 = W + 4 * (size_t)L_CHUNK * NP;
    const int cc0 = (c0     < N_BND) ? c0     : N_BND - 1;
    const int cc1 = (c0 + 1 < N_BND) ? c0 + 1 : N_BND - 1;
    const int cc2 = (c0 + 2 < N_BND) ? c0 + 2 : N_BND - 1;
    const int cc3 = (c0 + 3 < N_BND) ? c0 + 3 : N_BND - 1;
    const int nb0 = cc0 * L_CHUNK + L_CHUNK - 1;
    const int nb1 = cc1 * L_CHUNK + L_CHUNK - 1;
    const int nb2 = cc2 * L_CHUNK + L_CHUNK - 1;
    const int nb3 = cc3 * L_CHUNK + L_CHUNK - 1;
    float g0 = 0.f, g1 = 0.f, g2 = 0.f, g3 = 0.f;
    #pragma unroll 2
    for (int m = 0; m < L_CHUNK; ++m) {
        const float4 a0 = tau[nb0 - m];
        const float4 a1 = tau[nb1 - m];
        const float4 a2 = tau[nb2 - m];
        const float4 a3 = tau[nb3 - m];
        const size_t o = (size_t)m * NP + r;
        const float w0 = W0[o], w1 = W1[o], w2 = W2[o], w3 = W3[o], w4 = W4[o];
        float t;
        t = w0; t = fmaf(a0.x, w1, t); t = fmaf(a0.y, w2, t);
        t = fmaf(a0.z, w3, t); t = fmaf(a0.w, w4, t); g0 += t;
        t = w0; t = fmaf(a1.x, w1, t); t = fmaf(a1.y, w2, t);
        t = fmaf(a1.z, w3, t); t = fmaf(a1.w, w4, t); g1 += t;
        t = w0; t = fmaf(a2.x, w1, t); t = fmaf(a2.y, w2, t);
        t = fmaf(a2.z, w3, t); t = fmaf(a2.w, w4, t); g2 += t;
        t = w0; t = fmaf(a3.x, w1, t); t = fmaf(a3.y, w2, t);
        t = fmaf(a3.z, w3, t); t = fmaf(a3.w, w4, t); g3 += t;
    }
    G[(size_t)(c0    ) * NP + r] = (c0     < N_BND) ? g0 : 0.f;
    G[(size_t)(c0 + 1) * NP + r] = (c0 + 1 < N_BND) ? g1 : 0.f;
    G[(size_t)(c0 + 2) * NP + r] = (c0 + 2 < N_BND) ? g2 : 0.f;
    G[(size_t)(c0 + 3) * NP + r] = (c0 + 3 < N_BND) ? g3 : 0.f;
}

// ---------------------------------------------------------------------------
// Engine helpers.
// Lane l's accumulators cover rows {4l+k, k<4} and {256+l} of the wave's
// 40-column strip [40w, 40w+40) (row remap so partial writes vectorize).
__device__ __forceinline__ void load_pfrag(const float* __restrict__ Psrc,
                                           vf2 p[5][20], int l, int w)
{
    #pragma unroll
    for (int k = 0; k < 5; ++k) {
        const int row = (k < 4) ? (4 * l + k) : (256 + l);
        const float* Pr = Psrc + (size_t)row * NP + 40 * w;
        #pragma unroll
        for (int j4 = 0; j4 < 10; ++j4) {
            const float4 v4 = *(const float4*)(Pr + 4 * j4);
            vf2 a; a.x = v4.x; a.y = v4.y;
            vf2 b; b.x = v4.z; b.y = v4.w;
            p[k][2 * j4] = a;
            p[k][2 * j4 + 1] = b;
        }
    }
    #pragma unroll
    for (int k = 0; k < 5; ++k)
        #pragma unroll
        for (int jj = 0; jj < 20; jj += 4)
            PIN4(p[k][jj], p[k][jj + 1], p[k][jj + 2], p[k][jj + 3]);
}

// FMA phase: partial dots of this wave's rows over cols [40w,40w+40), y read
// from LDS broadcast; partials written b128 (rows 4l..4l+3) + b32 (256+l).
__device__ __forceinline__ void fma_phase(const vf2 p[5][20],
                                          const float* __restrict__ yb,
                                          float* __restrict__ pw, int l)
{
    vf2 a0 = {0.f, 0.f}, a1 = {0.f, 0.f}, a2 = {0.f, 0.f},
        a3 = {0.f, 0.f}, a4 = {0.f, 0.f};
    #pragma unroll
    for (int j4 = 0; j4 < 10; ++j4) {
        const float4 yv = *(const float4*)(yb + 4 * j4);
        vf2 y01; y01.x = yv.x; y01.y = yv.y;
        vf2 y23; y23.x = yv.z; y23.y = yv.w;
        const int jj = 2 * j4;
        PKFMA(a0, p[0][jj], y01); PKFMA(a0, p[0][jj + 1], y23);
        PKFMA(a1, p[1][jj], y01); PKFMA(a1, p[1][jj + 1], y23);
        PKFMA(a2, p[2][jj], y01); PKFMA(a2, p[2][jj + 1], y23);
        PKFMA(a3, p[3][jj], y01); PKFMA(a3, p[3][jj + 1], y23);
        PKFMA(a4, p[4][jj], y01); PKFMA(a4, p[4][jj + 1], y23);
    }
    float4 h4;
    h4.x = a0.x + a0.y;
    h4.y = a1.x + a1.y;
    h4.z = a2.x + a2.y;
    h4.w = a3.x + a3.y;
    *(float4*)(pw + 4 * l) = h4;          // rows 4l..4l+3 (16B aligned)
    pw[256 + l] = a4.x + a4.y;            // row 256+l
}

// Reduce row r: sum the 8 waves' partials (partials stored at [wave][row]).
__device__ __forceinline__ float reduce8(const float* __restrict__ pb, int r)
{
    float s = pb[r];
    #pragma unroll
    for (int k = 1; k < 8; ++k) s += pb[k * NP + r];
    return s;
}

// ---------------------------------------------------------------------------
// Level-2 boundary: Z_{g+1} = P^2048 Z_g + S4_g.  1 WG x 512, 29 steps.
__global__ ENGINE_LO void bscan_kernel(
    const float* __restrict__ PK, const float* __restrict__ S4,
    const float* __restrict__ iv, float* __restrict__ Z)
{
    const int tid = threadIdx.x;
    const int w = tid >> 6, l = tid & 63;
    vf2 p[5][20];
    load_pfrag(PK, p, l, w);

    __shared__ float ybuf[NP];
    __shared__ float part[2 * 8 * NP];
    __shared__ float ring[NSCAN * NP];

    const int r = 40 * w + l;   // valid when l < 40
    if (tid < NP) {
        const float y0 = (tid < NN) ? iv[tid] : 0.f;
        ybuf[tid] = y0;
        Z[tid] = y0;
    }
    float sv = (l < 40) ? S4[r] : 0.f;
    __syncthreads();

    for (int g = 0; g < NSCAN; ++g) {
        float* pb = part + (g & 1) * 8 * NP;
        fma_phase(p, ybuf + 40 * w, pb + w * NP, l);
        const float svn = (l < 40 && g + 1 < NSCAN)
                        ? S4[(size_t)(g + 1) * NP + r] : 0.f;
        __syncthreads();
        if (l < 40) {
            const float yn = reduce8(pb, r) + sv;
            ybuf[r] = yn;
            ring[g * NP + r] = yn;
        }
        sv = svn;
    }
    __syncthreads();
    for (int s2 = 0; s2 < NSCAN; ++s2)
        for (int j = tid; j < NP; j += 512)
            Z[(size_t)(s2 + 1) * NP + j] = ring[s2 * NP + j];
}

// ---------------------------------------------------------------------------
// Level-2 refill: Y_{16g+i+1} = P^128 Y_{16g+i} + G_{16g+i}.  30 WGs x 512.
__global__ ENGINE_LO void brefill_kernel(
    const float* __restrict__ PL, const float* __restrict__ G,
    const float* __restrict__ Z, float* __restrict__ Y)
{
    const int tid = threadIdx.x;
    const int w = tid >> 6, l = tid & 63;
    vf2 p[5][20];
    load_pfrag(PL, p, l, w);

    __shared__ float ybuf[NP];
    __shared__ float part[2 * 8 * NP];
    __shared__ float ring[16 * NP];

    const int g = blockIdx.x;
    const int nsteps = (16 * g + 16 <= N_BND) ? 16 : (N_BND - 16 * g);
    const int r = 40 * w + l;
    if (tid < NP) {
        const float z = Z[(size_t)g * NP + tid];
        ybuf[tid] = z;
        if (g == 0) Y[tid] = z;
    }
    float gv = (l < 40) ? G[(size_t)(16 * g) * NP + r] : 0.f;
    __syncthreads();

    for (int i = 0; i < nsteps; ++i) {
        float* pb = part + (i & 1) * 8 * NP;
        fma_phase(p, ybuf + 40 * w, pb + w * NP, l);
        const float gvn = (l < 40 && i + 1 < nsteps)
                        ? G[(size_t)(16 * g + i + 1) * NP + r] : 0.f;
        __syncthreads();
        if (l < 40) {
            const float yn = reduce8(pb, r) + gv;
            ybuf[r] = yn;
            ring[i * NP + r] = yn;
        }
        gv = gvn;
    }
    __syncthreads();
    for (int s2 = 0; s2 < nsteps; ++s2)
        for (int j = tid; j < NP; j += 512)
            Y[(size_t)(16 * g + 1 + s2) * NP + j] = ring[s2 * NP + j];
}

// ---------------------------------------------------------------------------
// Level-1 refill (r11/r14 structure, proven ~274us): 235 WGs x 512; WG b
// advances TWO chains (chunks 2b and 2b+1) half a step apart, sharing one
// register-resident P:
//   phase1: fmaA(i) + reduceB(i-1)  -> barrier
//   phase2: fmaB(i) + reduceA(i)    -> barrier
__global__ ENGINE_LO void refill_kernel(
    const float* __restrict__ P, const float* __restrict__ uv,
    const float4* __restrict__ tau, const float* __restrict__ Y,
    float* __restrict__ out)
{
    const int tid = threadIdx.x;
    const int w = tid >> 6, l = tid & 63;
    vf2 p[5][20];
    load_pfrag(P, p, l, w);

    __shared__ float ybufA[NP], ybufB[NP];
    __shared__ float partA[8 * NP], partB[8 * NP];
    __shared__ float ringA[8 * NP], ringB[8 * NP];
    __shared__ float4 tausA[8], tausB[8];

    const int r = 40 * w + l;
    float du0 = 0.f, du1 = 0.f, du2 = 0.f, du3 = 0.f, dd = 0.f;
    if (l < 40) {
        du0 = uv[r]; du1 = uv[NP + r]; du2 = uv[2 * NP + r];
        du3 = uv[3 * NP + r]; dd = uv[4 * NP + r];
    }

    const int b = blockIdx.x;
    const int cA = 2 * b, cB = 2 * b + 1;
    const int n0A = cA * L_CHUNK;
    const int n0B = cB * L_CHUNK;
    const int nA = (n0A + L_CHUNK < TS) ? L_CHUNK : (TS - n0A);
    const bool hasB = (cB < N_CHUNK);   // when true, nB == nA == 128

    if (tid < NP) {
        ybufA[tid] = Y[(size_t)cA * NP + tid];
        if (hasB) ybufB[tid] = Y[(size_t)cB * NP + tid];
    }
    if (tid < 8) {
        if (tid < nA) tausA[tid] = tau[n0A + tid];
        if (hasB) tausB[tid] = tau[n0B + tid];
    }
    int wsA = 0, wsB = 0;
    __syncthreads();

    for (int i = 0; i < nA; ++i) {
        // ---------------- phase 1: flushA? ; fmaA(i) ; reduceB(i-1)
        if (i - wsA == 8) {
            #pragma unroll 1
            for (int s2 = 0; s2 < 8; ++s2) {
                const size_t row = (size_t)(n0A + wsA + 1 + s2);
                for (int j = tid; j < NN; j += 512)
                    out[row * NN + j] = ringA[s2 * NP + j];
            }
            wsA = i;
            if (tid < 8 && i + tid < nA) tausA[tid] = tau[n0A + i + tid];
        }
        fma_phase(p, ybufA + 40 * w, partA + w * NP, l);
        if (hasB && i > 0) {
            const int sb = (i - 1) - wsB;
            const float4 a = tausB[sb];
            if (l < 40) {
                float yn = reduce8(partB, r) + dd;
                yn = fmaf(a.x, du0, yn);
                yn = fmaf(a.y, du1, yn);
                yn = fmaf(a.z, du2, yn);
                yn = fmaf(a.w, du3, yn);
                ybufB[r] = yn;
                ringB[sb * NP + r] = yn;
            }
        }
        __syncthreads();
        // ---------------- phase 2: flushB? ; fmaB(i) ; reduceA(i)
        if (hasB && i - wsB == 8) {
            #pragma unroll 1
            for (int s2 = 0; s2 < 8; ++s2) {
                const size_t row = (size_t)(n0B + wsB + 1 + s2);
                for (int j = tid; j < NN; j += 512)
                    out[row * NN + j] = ringB[s2 * NP + j];
            }
            wsB = i;
            if (tid < 8) tausB[tid] = tau[n0B + i + tid];
        }
        if (hasB) fma_phase(p, ybufB + 40 * w, partB + w * NP, l);
        {
            const int sa = i - wsA;
            const float4 a = tausA[sa];
            if (l < 40) {
                float yn = reduce8(partA, r) + dd;
                yn = fmaf(a.x, du0, yn);
                yn = fmaf(a.y, du1, yn);
                yn = fmaf(a.z, du2, yn);
                yn = fmaf(a.w, du3, yn);
                ybufA[r] = yn;
                ringA[sa * NP + r] = yn;
            }
        }
        __syncthreads();
    }

    // post-loop: reduceB(nA-1), then tail flushes
    if (hasB) {
        const int sb = (nA - 1) - wsB;
        const float4 a = tausB[sb];
        if (l < 40) {
            float yn = reduce8(partB, r) + dd;
            yn = fmaf(a.x, du0, yn);
            yn = fmaf(a.y, du1, yn);
            yn = fmaf(a.z, du2, yn);
            yn = fmaf(a.w, du3, yn);
            ringB[sb * NP + r] = yn;
        }
    }
    __syncthreads();
    {
        const int cntA = nA - wsA;
        for (int s2 = 0; s2 < cntA; ++s2) {
            const size_t row = (size_t)(n0A + wsA + 1 + s2);
            for (int j = tid; j < NN; j += 512)
                out[row * NN + j] = ringA[s2 * NP + j];
        }
        if (hasB) {
            const int cntB = nA - wsB;
            for (int s2 = 0; s2 < cntB; ++s2) {
                const size_t row = (size_t)(n0B + wsB + 1 + s2);
                for (int j = tid; j < NN; j += 512)
                    out[row * NN + j] = ringB[s2 * NP + j];
            }
        }
    }
}

// ---------------------------------------------------------------------------
extern "C" void kernel_launch(void* const* d_in, const int* in_sizes, int n_in,
                              void* d_out, int out_size, void* d_ws, size_t ws_size,
                              hipStream_t stream)
{
    const float* params = (const float*)d_in[0];
    const float* tlo    = (const float*)d_in[1];
    const float* thi    = (const float*)d_in[2];
    const float* B      = (const float*)d_in[3];
    const float* tout_t = (const float*)d_in[4];
    const float* tout_v = (const float*)d_in[5];
    const float* iv     = (const float*)d_in[6];
    const int*   t0     = (const int*)d_in[8];
    float* out = (float*)d_out;
    float* ws  = (float*)d_ws;

    float*  M    = ws + WS_M;
    float*  MT   = ws + WS_MT;
    float*  M2   = ws + WS_M2;
    float*  P    = ws + WS_P;
    float*  UV   = ws + WS_UV;
    float*  B0C  = ws + WS_B0C;
    float4* TAU  = (float4*)(ws + WS_TAU);
    float*  W    = ws + WS_W;
    float*  G    = ws + WS_G;
    float*  Y    = ws + WS_Y;
    float*  Z    = ws + WS_Z;
    float*  SA   = ws + WS_SA;
    float*  SB   = ws + WS_SB;
    float*  PL   = ws + WS_PL;
    float*  PA   = ws + WS_PA;
    float*  PB   = ws + WS_PB;
    float*  PT   = ws + WS_PT;     // slot j: transpose of P^(2^j)

    // Phase A (fused): buildrow + b0c + tau in one launch
    phaseA_kernel<<<619, 320, 0, stream>>>(params, tlo, thi, B, tout_t,
                                           tout_v, t0, M, MT, B0C, TAU);

    // M2 = M@M fused with vec (forcing vectors, W seed, out row 0)
    mm4r_vec_kernel<<<81, 320, 0, stream>>>(M, M2, MT, B0C, UV, iv, W, out);

    // P = M2@(M/6+M2/24) + I + M + M2/2 (+ PT[0])
    matmulP<<<dim3(5, 80), 64, 0, stream>>>(M2, M, P, PT);

    // Squaring ladder with riders (squaring: 80 blocks, 4 rows/thread).
    // j=0..6: W doubling riders; dst of j=6 is PL = P^128.
    const float* src = P;
    for (int j = 0; j < 7; ++j) {
        float* dst = (j == 6) ? PL : ((j & 1) ? PB : PA);
        const int aux = ((5 << j) + 3) / 4;
        fat_kernel<<<80 + aux, 320, 0, stream>>>(src, dst, PT, j, W,
                                                 nullptr, nullptr, 0);
        src = dst;
    }
    // Boundary forcing sums over each 128-step chunk (4 c's per block).
    gsum_kernel<<<dim3(5, NB_PAD / 4), 64, 0, stream>>>(W, TAU, G);
    // j=7..10: pair-combine riders 480 -> 240 -> 120 -> 60 -> 30 group sums.
    const float* Spp[5] = { G, SA, SB, SA, SB };
    for (int j = 7; j < 11; ++j) {
        float* dst = (j & 1) ? PB : PA;
        const int npairs = 30720 >> j;     // 240, 120, 60, 30
        const int aux = (npairs + 3) / 4;
        fat_kernel<<<80 + aux, 320, 0, stream>>>(src, dst, PT, j, W,
                                                 Spp[j - 7], (float*)Spp[j - 6], npairs);
        src = dst;
    }
    // src == PA == P^2048; SB holds 30 group sums

    // Level-2 boundary chain + level-2 refill of Y
    bscan_kernel<<<1, 512, 0, stream>>>(PA, SB, iv, Z);
    brefill_kernel<<<N_GRP, 512, 0, stream>>>(PL, G, Z, Y);

    // Level-1 parallel refill (2 chains per WG)
    refill_kernel<<<N_WG2, 512, 0, stream>>>(P, UV, TAU, Y, out);
}